// Round 1
// baseline (611.127 us; speedup 1.0000x reference)
//
#include <hip/hip_runtime.h>
#include <cstdint>

// ---------- helpers ----------
__device__ __forceinline__ unsigned short f2bf(float x) {
  unsigned int u = __float_as_uint(x);
  u += 0x7FFFu + ((u >> 16) & 1u);   // round-to-nearest-even
  return (unsigned short)(u >> 16);
}
__device__ __forceinline__ float bf2f(unsigned int h) {
  return __uint_as_float(h << 16);
}

// ---------- 1. r[t][n][m] = relu(q[n] @ W1[t]) , m in [0,1024) ----------
__global__ __launch_bounds__(256) void k_qattn1(const float* __restrict__ q,
                                                const float* __restrict__ W1,
                                                float* __restrict__ r) {
  const int n0 = blockIdx.x * 4;
  const int mh = blockIdx.y;      // m-half: 0 or 1
  const int t  = blockIdx.z;
  const int tid = threadIdx.x;
  __shared__ float qs[4][512];
  for (int idx = tid; idx < 4 * 512; idx += 256)
    qs[idx >> 9][idx & 511] = q[(size_t)(n0 + (idx >> 9)) * 512 + (idx & 511)];
  __syncthreads();
  const float* Wb = W1 + ((size_t)t * 512) * 1024 + mh * 512;
  float acc[4][2] = {};
  for (int k = 0; k < 512; ++k) {
    const float* row = Wb + (size_t)k * 1024;
    float w0 = row[tid];
    float w1 = row[tid + 256];
#pragma unroll
    for (int nn = 0; nn < 4; ++nn) {
      float qv = qs[nn][k];
      acc[nn][0] = fmaf(qv, w0, acc[nn][0]);
      acc[nn][1] = fmaf(qv, w1, acc[nn][1]);
    }
  }
#pragma unroll
  for (int nn = 0; nn < 4; ++nn) {
    float* ro = r + ((size_t)(t * 64 + n0 + nn)) * 1024 + mh * 512;
    ro[tid]       = fmaxf(acc[nn][0], 0.f);
    ro[tid + 256] = fmaxf(acc[nn][1], 0.f);
  }
}

// ---------- 2. g = sigmoid(r @ W2[t]); store gal_T[t][d][n], gar_T[t][d][n] ----------
__global__ __launch_bounds__(256) void k_qattn2(const float* __restrict__ r,
                                                const float* __restrict__ W2,
                                                const float* __restrict__ a_type,
                                                float* __restrict__ galT,
                                                float* __restrict__ garT) {
  const int n0 = blockIdx.x * 4;
  const int mh = blockIdx.y;
  const int t  = blockIdx.z;
  const int tid = threadIdx.x;
  __shared__ float rs[4][1024];
  for (int idx = tid; idx < 4 * 1024; idx += 256)
    rs[idx >> 10][idx & 1023] =
        r[((size_t)(t * 64 + n0 + (idx >> 10))) * 1024 + (idx & 1023)];
  __syncthreads();
  const float* Wb = W2 + ((size_t)t << 20) + mh * 512;
  float acc[4][2] = {};
  for (int k = 0; k < 1024; ++k) {
    const float* row = Wb + (size_t)k * 1024;
    float w0 = row[tid];
    float w1 = row[tid + 256];
#pragma unroll
    for (int nn = 0; nn < 4; ++nn) {
      float rv = rs[nn][k];
      acc[nn][0] = fmaf(rv, w0, acc[nn][0]);
      acc[nn][1] = fmaf(rv, w1, acc[nn][1]);
    }
  }
#pragma unroll
  for (int nn = 0; nn < 4; ++nn) {
#pragma unroll
    for (int mm = 0; mm < 2; ++mm) {
      int ml = tid + mm * 256;
      int mg = mh * 512 + ml;
      float g  = 1.f / (1.f + __expf(-acc[nn][mm]));
      float ga = g * a_type[t * 1024 + mg];
      if (mh == 0) galT[((size_t)t * 512 + mg) * 64 + (n0 + nn)] = ga;
      else         garT[((size_t)t * 512 + (mg - 512)) * 64 + (n0 + nn)] = ga;
    }
  }
}

// ---------- 3. u[t][n][k] = sum_d W[t][k][d]*gal[t][n][d] ; v likewise ----------
__global__ __launch_bounds__(256) void k_uv(const float* __restrict__ W,
                                            const float* __restrict__ galT,
                                            const float* __restrict__ garT,
                                            float* __restrict__ u,
                                            float* __restrict__ v) {
  const int t    = blockIdx.y;
  const int wid  = threadIdx.x >> 6;
  const int lane = threadIdx.x & 63;     // lane = n
  const int k0   = blockIdx.x * 16 + wid * 4;
  const float* gl = galT + (size_t)t * 512 * 64;
  const float* gr = garT + (size_t)t * 512 * 64;
  const float* Wb = W + ((size_t)t * 512 + k0) * 512;
  float au[4] = {}, av[4] = {};
  for (int d = 0; d < 512; ++d) {
    float g1 = gl[d * 64 + lane];
    float g2 = gr[d * 64 + lane];
#pragma unroll
    for (int kk = 0; kk < 4; ++kk) {
      float w = Wb[(size_t)kk * 512 + d];
      au[kk] = fmaf(w, g1, au[kk]);
      av[kk] = fmaf(w, g2, av[kk]);
    }
  }
#pragma unroll
  for (int kk = 0; kk < 4; ++kk) {
    u[((size_t)t * 64 + lane) * 512 + k0 + kk] = au[kk];
    v[((size_t)t * 64 + lane) * 512 + k0 + kk] = av[kk];
  }
}

// ---------- 4. left[t][n][i] = input[n][i] . u[t][n] ; right likewise ----------
__global__ __launch_bounds__(256) void k_lr(const float* __restrict__ x,
                                            const float* __restrict__ u,
                                            const float* __restrict__ v,
                                            float* __restrict__ left,
                                            float* __restrict__ right) {
  const int n = blockIdx.y;
  const int itile = blockIdx.x;
  const int tid = threadIdx.x;
  const int wid = tid >> 6, lane = tid & 63;
  // transposed layout [t][e][lane] to keep LDS reads conflict-free
  __shared__ float us[3][8][64], vs[3][8][64];
  for (int idx = tid; idx < 3 * 512; idx += 256) {
    int t = idx >> 9, k = idx & 511;
    us[t][k & 7][k >> 3] = u[((size_t)t * 64 + n) * 512 + k];
    vs[t][k & 7][k >> 3] = v[((size_t)t * 64 + n) * 512 + k];
  }
  __syncthreads();
  for (int ii = 0; ii < 16; ++ii) {
    int i = itile * 64 + wid * 16 + ii;
    const float4* row = (const float4*)(x + ((size_t)n * 512 + i) * 512) + lane * 2;
    float4 f0 = row[0], f1 = row[1];
    float xe[8] = {f0.x, f0.y, f0.z, f0.w, f1.x, f1.y, f1.z, f1.w};
    float pl[3] = {}, pr[3] = {};
#pragma unroll
    for (int t = 0; t < 3; ++t) {
#pragma unroll
      for (int e = 0; e < 8; ++e) {
        pl[t] = fmaf(xe[e], us[t][e][lane], pl[t]);
        pr[t] = fmaf(xe[e], vs[t][e][lane], pr[t]);
      }
    }
#pragma unroll
    for (int t = 0; t < 3; ++t) {
      for (int off = 32; off > 0; off >>= 1) {
        pl[t] += __shfl_xor(pl[t], off);
        pr[t] += __shfl_xor(pr[t], off);
      }
    }
    if (lane == 0) {
#pragma unroll
      for (int t = 0; t < 3; ++t) {
        left [((size_t)t * 64 + n) * 512 + i] = pl[t];
        right[((size_t)t * 64 + n) * 512 + i] = pr[t];
      }
    }
  }
}

// ---------- 5. h2[n][i][d] (bf16) = input[n] @ W_type[2] ----------
__global__ __launch_bounds__(256) void k_gemm_h2(const float* __restrict__ x,
                                                 const float* __restrict__ Wt,
                                                 unsigned short* __restrict__ h2) {
  const int n  = blockIdx.y;
  const int ib = blockIdx.x >> 2, db = blockIdx.x & 3;
  const int i0 = ib * 128, d0 = db * 128;
  const int tid = threadIdx.x;
  const int tx = tid & 15, ty = tid >> 4;
  __shared__ float Ast[16][132];
  __shared__ float Bs[16][132];
  float acc[8][8] = {};
  const float* xb = x + ((size_t)n * 512 + i0) * 512;
  const int la_i = tid >> 1;
  const int la_k = (tid & 1) * 8;
  const int lb_k = tid >> 4;
  const int lb_d = (tid & 15) * 8;
  for (int kc = 0; kc < 512; kc += 16) {
    __syncthreads();
    {
      const float* p = xb + (size_t)la_i * 512 + kc + la_k;
      float4 f0 = *(const float4*)p;
      float4 f1 = *(const float4*)(p + 4);
      Ast[la_k + 0][la_i] = f0.x; Ast[la_k + 1][la_i] = f0.y;
      Ast[la_k + 2][la_i] = f0.z; Ast[la_k + 3][la_i] = f0.w;
      Ast[la_k + 4][la_i] = f1.x; Ast[la_k + 5][la_i] = f1.y;
      Ast[la_k + 6][la_i] = f1.z; Ast[la_k + 7][la_i] = f1.w;
    }
    {
      const float* p = Wt + (size_t)(kc + lb_k) * 512 + d0 + lb_d;
      float4 f0 = *(const float4*)p;
      float4 f1 = *(const float4*)(p + 4);
      *(float4*)&Bs[lb_k][lb_d]     = f0;
      *(float4*)&Bs[lb_k][lb_d + 4] = f1;
    }
    __syncthreads();
#pragma unroll
    for (int kk = 0; kk < 16; ++kk) {
      float aa[8], bb[8];
      *(float4*)&aa[0] = *(const float4*)&Ast[kk][ty * 4];
      *(float4*)&aa[4] = *(const float4*)&Ast[kk][64 + ty * 4];
      *(float4*)&bb[0] = *(const float4*)&Bs[kk][tx * 4];
      *(float4*)&bb[4] = *(const float4*)&Bs[kk][64 + tx * 4];
#pragma unroll
      for (int rr = 0; rr < 8; ++rr)
#pragma unroll
        for (int cc = 0; cc < 8; ++cc)
          acc[rr][cc] = fmaf(aa[rr], bb[cc], acc[rr][cc]);
    }
  }
#pragma unroll
  for (int rr = 0; rr < 8; ++rr) {
    int row = (rr < 4) ? (ty * 4 + rr) : (64 + ty * 4 + rr - 4);
    unsigned short* op = h2 + ((size_t)n * 512 + i0 + row) * 512 + d0;
#pragma unroll
    for (int half = 0; half < 2; ++half) {
      int col = half * 64 + tx * 4;
      int cb = half * 4;
      uint2 pk;
      pk.x = ((unsigned)f2bf(acc[rr][cb + 1]) << 16) | f2bf(acc[rr][cb + 0]);
      pk.y = ((unsigned)f2bf(acc[rr][cb + 3]) << 16) | f2bf(acc[rr][cb + 2]);
      *(uint2*)(op + col) = pk;
    }
  }
}

// ---------- 6. masked softmax over j ; coefs bf16 ----------
__global__ __launch_bounds__(256) void k_softmax(const int* __restrict__ adj,
                                                 const float* __restrict__ left,
                                                 const float* __restrict__ right,
                                                 unsigned short* __restrict__ coefs) {
  const int n = blockIdx.y;
  const int wid = threadIdx.x >> 6, lane = threadIdx.x & 63;
  const int i = blockIdx.x * 4 + wid;
  __shared__ float rights[3][8][64];
  for (int idx = threadIdx.x; idx < 3 * 512; idx += 256) {
    int t = idx >> 9, j = idx & 511;
    rights[t][j & 7][j >> 3] = right[((size_t)t * 64 + n) * 512 + j];
  }
  __syncthreads();
  float l0 = left[((size_t)0 * 64 + n) * 512 + i];
  float l1 = left[((size_t)1 * 64 + n) * 512 + i];
  float l2 = left[((size_t)2 * 64 + n) * 512 + i];
  const int4* ap = (const int4*)(adj + ((size_t)n * 512 + i) * 512) + lane * 2;
  int4 a0 = ap[0], a1 = ap[1];
  int av[8] = {a0.x, a0.y, a0.z, a0.w, a1.x, a1.y, a1.z, a1.w};
  float s[8];
#pragma unroll
  for (int e = 0; e < 8; ++e) {
    int tv = av[e];
    if (tv == 0) s[e] = -9e15f;
    else {
      float lv = (tv == 1) ? l0 : (tv == 2) ? l1 : l2;
      float xv = lv + rights[tv - 1][e][lane];
      s[e] = (xv >= 0.f) ? xv : 0.2f * xv;
    }
  }
  float m = s[0];
#pragma unroll
  for (int e = 1; e < 8; ++e) m = fmaxf(m, s[e]);
  for (int off = 32; off > 0; off >>= 1) m = fmaxf(m, __shfl_xor(m, off));
  float p[8], sum = 0.f;
#pragma unroll
  for (int e = 0; e < 8; ++e) { p[e] = __expf(s[e] - m); sum += p[e]; }
  for (int off = 32; off > 0; off >>= 1) sum += __shfl_xor(sum, off);
  float inv = 1.f / sum;
  uint4 o;
  o.x = ((unsigned)f2bf(p[1] * inv) << 16) | f2bf(p[0] * inv);
  o.y = ((unsigned)f2bf(p[3] * inv) << 16) | f2bf(p[2] * inv);
  o.z = ((unsigned)f2bf(p[5] * inv) << 16) | f2bf(p[4] * inv);
  o.w = ((unsigned)f2bf(p[7] * inv) << 16) | f2bf(p[6] * inv);
  *(uint4*)(coefs + ((size_t)n * 512 + i) * 512 + lane * 8) = o;
}

// ---------- 7. out[n][j][d] = sum_i coefs[n][i][j] * h2[n][i][d] ----------
__global__ __launch_bounds__(256) void k_gemm_out(const unsigned short* __restrict__ coefs,
                                                  const unsigned short* __restrict__ h2,
                                                  float* __restrict__ out) {
  const int n  = blockIdx.y;
  const int jb = blockIdx.x >> 2, db = blockIdx.x & 3;
  const int j0 = jb * 128, d0 = db * 128;
  const int tid = threadIdx.x;
  const int tx = tid & 15, ty = tid >> 4;
  __shared__ float Ast[16][132];
  __shared__ float Bs[16][132];
  float acc[8][8] = {};
  const int lk = tid >> 4;
  const int lc = (tid & 15) * 8;
  for (int kc = 0; kc < 512; kc += 16) {
    __syncthreads();
    {
      const unsigned short* p = coefs + ((size_t)n * 512 + kc + lk) * 512 + j0 + lc;
      uint4 q = *(const uint4*)p;
      Ast[lk][lc + 0] = bf2f(q.x & 0xFFFFu); Ast[lk][lc + 1] = bf2f(q.x >> 16);
      Ast[lk][lc + 2] = bf2f(q.y & 0xFFFFu); Ast[lk][lc + 3] = bf2f(q.y >> 16);
      Ast[lk][lc + 4] = bf2f(q.z & 0xFFFFu); Ast[lk][lc + 5] = bf2f(q.z >> 16);
      Ast[lk][lc + 6] = bf2f(q.w & 0xFFFFu); Ast[lk][lc + 7] = bf2f(q.w >> 16);
    }
    {
      const unsigned short* p = h2 + ((size_t)n * 512 + kc + lk) * 512 + d0 + lc;
      uint4 q = *(const uint4*)p;
      Bs[lk][lc + 0] = bf2f(q.x & 0xFFFFu); Bs[lk][lc + 1] = bf2f(q.x >> 16);
      Bs[lk][lc + 2] = bf2f(q.y & 0xFFFFu); Bs[lk][lc + 3] = bf2f(q.y >> 16);
      Bs[lk][lc + 4] = bf2f(q.z & 0xFFFFu); Bs[lk][lc + 5] = bf2f(q.z >> 16);
      Bs[lk][lc + 6] = bf2f(q.w & 0xFFFFu); Bs[lk][lc + 7] = bf2f(q.w >> 16);
    }
    __syncthreads();
#pragma unroll
    for (int kk = 0; kk < 16; ++kk) {
      float aa[8], bb[8];
      *(float4*)&aa[0] = *(const float4*)&Ast[kk][ty * 4];
      *(float4*)&aa[4] = *(const float4*)&Ast[kk][64 + ty * 4];
      *(float4*)&bb[0] = *(const float4*)&Bs[kk][tx * 4];
      *(float4*)&bb[4] = *(const float4*)&Bs[kk][64 + tx * 4];
#pragma unroll
      for (int rr = 0; rr < 8; ++rr)
#pragma unroll
        for (int cc = 0; cc < 8; ++cc)
          acc[rr][cc] = fmaf(aa[rr], bb[cc], acc[rr][cc]);
    }
  }
#pragma unroll
  for (int rr = 0; rr < 8; ++rr) {
    int row = (rr < 4) ? (ty * 4 + rr) : (64 + ty * 4 + rr - 4);
    float* op = out + ((size_t)n * 512 + j0 + row) * 512 + d0;
    *(float4*)(op + tx * 4)      = make_float4(acc[rr][0], acc[rr][1], acc[rr][2], acc[rr][3]);
    *(float4*)(op + 64 + tx * 4) = make_float4(acc[rr][4], acc[rr][5], acc[rr][6], acc[rr][7]);
  }
}

extern "C" void kernel_launch(void* const* d_in, const int* in_sizes, int n_in,
                              void* d_out, int out_size, void* d_ws, size_t ws_size,
                              hipStream_t stream) {
  const float* input  = (const float*)d_in[0];
  const int*   adj    = (const int*)d_in[1];
  // d_in[2] entity_mask: unused by reference
  const float* query  = (const float*)d_in[3];
  const float* W_type = (const float*)d_in[4];
  const float* a_type = (const float*)d_in[5];
  const float* W1     = (const float*)d_in[6];
  const float* W2     = (const float*)d_in[7];
  float* out = (float*)d_out;

  char* ws = (char*)d_ws;
  float* r     = (float*)(ws);                  //   786,432 B  [3][64][1024]
  float* galT  = (float*)(ws + 786432);         //   393,216 B  [3][512][64]
  float* garT  = (float*)(ws + 1179648);        //   393,216 B
  float* u     = (float*)(ws + 1572864);        //   393,216 B  [3][64][512]
  float* v     = (float*)(ws + 1966080);        //   393,216 B
  float* left  = (float*)(ws + 2359296);        //   393,216 B  [3][64][512]
  float* right = (float*)(ws + 2752512);        //   393,216 B
  unsigned short* h2    = (unsigned short*)(ws + 3145728);   // 33,554,432 B bf16
  unsigned short* coefs = (unsigned short*)(ws + 36700160);  // 33,554,432 B bf16
  // total ws use: 70,254,592 B

  k_qattn1 <<<dim3(16, 2, 3), 256, 0, stream>>>(query, W1, r);
  k_qattn2 <<<dim3(16, 2, 3), 256, 0, stream>>>(r, W2, a_type, galT, garT);
  k_uv     <<<dim3(32, 3),    256, 0, stream>>>(W_type, galT, garT, u, v);
  k_lr     <<<dim3(8, 64),    256, 0, stream>>>(input, u, v, left, right);
  k_gemm_h2<<<dim3(16, 64),   256, 0, stream>>>(input, W_type + (size_t)2 * 512 * 512, h2);
  k_softmax<<<dim3(128, 64),  256, 0, stream>>>(adj, left, right, coefs);
  k_gemm_out<<<dim3(16, 64),  256, 0, stream>>>(coefs, h2, out);
}

// Round 2
// 330.176 us; speedup vs baseline: 1.8509x; 1.8509x over previous
//
#include <hip/hip_runtime.h>
#include <cstdint>

typedef unsigned short ushort_t;
typedef __attribute__((ext_vector_type(8))) short short8;
typedef __attribute__((ext_vector_type(4))) float f32x4;

// ---------- helpers ----------
__device__ __forceinline__ unsigned short f2bf(float x) {
  unsigned int u = __float_as_uint(x);
  u += 0x7FFFu + ((u >> 16) & 1u);   // round-to-nearest-even
  return (unsigned short)(u >> 16);
}
__device__ __forceinline__ float bf2f(unsigned int h) {
  return __uint_as_float(h << 16);
}

#define GLOAD16(gsrc, ldst)                                                        \
  __builtin_amdgcn_global_load_lds(                                                \
      (const __attribute__((address_space(1))) void*)(gsrc),                       \
      (__attribute__((address_space(3))) void*)(ldst), 16, 0, 0)

// ---------- 0a. input f32 -> bf16 ----------
__global__ __launch_bounds__(256) void k_conv(const float* __restrict__ x,
                                              unsigned short* __restrict__ y, int n4) {
  int i = blockIdx.x * 256 + threadIdx.x;
  for (; i < n4; i += gridDim.x * 256) {
    float4 f = ((const float4*)x)[i];
    ushort4 o;
    o.x = f2bf(f.x); o.y = f2bf(f.y); o.z = f2bf(f.z); o.w = f2bf(f.w);
    ((ushort4*)y)[i] = o;
  }
}

// ---------- 0b. WT[d][k] = bf16(W2[k][d]) ----------
__global__ __launch_bounds__(256) void k_wt(const float* __restrict__ W,
                                            unsigned short* __restrict__ WT) {
  __shared__ float t[64][68];
  const int k0 = blockIdx.y * 64, d0 = blockIdx.x * 64;
  for (int idx = threadIdx.x; idx < 4096; idx += 256) {
    int r = idx >> 6, c = idx & 63;
    t[r][c] = W[(size_t)(k0 + r) * 512 + d0 + c];
  }
  __syncthreads();
  for (int idx = threadIdx.x; idx < 4096; idx += 256) {
    int r = idx >> 6, c = idx & 63;     // r = d-local, c = k-local
    WT[(size_t)(d0 + r) * 512 + k0 + c] = f2bf(t[c][r]);
  }
}

// ---------- 1. r[t][n][m] = relu(q[n] @ W1[t]) ----------
__global__ __launch_bounds__(256) void k_qattn1(const float* __restrict__ q,
                                                const float* __restrict__ W1,
                                                float* __restrict__ r) {
  const int n0 = blockIdx.x * 4;
  const int mh = blockIdx.y;
  const int t  = blockIdx.z;
  const int tid = threadIdx.x;
  __shared__ float qs[4][512];
  for (int idx = tid; idx < 4 * 512; idx += 256)
    qs[idx >> 9][idx & 511] = q[(size_t)(n0 + (idx >> 9)) * 512 + (idx & 511)];
  __syncthreads();
  const float* Wb = W1 + ((size_t)t * 512) * 1024 + mh * 512;
  float acc[4][2] = {};
  for (int k = 0; k < 512; ++k) {
    const float* row = Wb + (size_t)k * 1024;
    float w0 = row[tid];
    float w1 = row[tid + 256];
#pragma unroll
    for (int nn = 0; nn < 4; ++nn) {
      float qv = qs[nn][k];
      acc[nn][0] = fmaf(qv, w0, acc[nn][0]);
      acc[nn][1] = fmaf(qv, w1, acc[nn][1]);
    }
  }
#pragma unroll
  for (int nn = 0; nn < 4; ++nn) {
    float* ro = r + ((size_t)(t * 64 + n0 + nn)) * 1024 + mh * 512;
    ro[tid]       = fmaxf(acc[nn][0], 0.f);
    ro[tid + 256] = fmaxf(acc[nn][1], 0.f);
  }
}

// ---------- 2. g = sigmoid(r @ W2[t]) ----------
__global__ __launch_bounds__(256) void k_qattn2(const float* __restrict__ r,
                                                const float* __restrict__ W2,
                                                const float* __restrict__ a_type,
                                                float* __restrict__ galT,
                                                float* __restrict__ garT) {
  const int n0 = blockIdx.x * 4;
  const int mh = blockIdx.y;
  const int t  = blockIdx.z;
  const int tid = threadIdx.x;
  __shared__ float rs[4][1024];
  for (int idx = tid; idx < 4 * 1024; idx += 256)
    rs[idx >> 10][idx & 1023] =
        r[((size_t)(t * 64 + n0 + (idx >> 10))) * 1024 + (idx & 1023)];
  __syncthreads();
  const float* Wb = W2 + ((size_t)t << 20) + mh * 512;
  float acc[4][2] = {};
  for (int k = 0; k < 1024; ++k) {
    const float* row = Wb + (size_t)k * 1024;
    float w0 = row[tid];
    float w1 = row[tid + 256];
#pragma unroll
    for (int nn = 0; nn < 4; ++nn) {
      float rv = rs[nn][k];
      acc[nn][0] = fmaf(rv, w0, acc[nn][0]);
      acc[nn][1] = fmaf(rv, w1, acc[nn][1]);
    }
  }
#pragma unroll
  for (int nn = 0; nn < 4; ++nn) {
#pragma unroll
    for (int mm = 0; mm < 2; ++mm) {
      int ml = tid + mm * 256;
      int mg = mh * 512 + ml;
      float g  = 1.f / (1.f + __expf(-acc[nn][mm]));
      float ga = g * a_type[t * 1024 + mg];
      if (mh == 0) galT[((size_t)t * 512 + mg) * 64 + (n0 + nn)] = ga;
      else         garT[((size_t)t * 512 + (mg - 512)) * 64 + (n0 + nn)] = ga;
    }
  }
}

// ---------- 3. u,v ----------
__global__ __launch_bounds__(256) void k_uv(const float* __restrict__ W,
                                            const float* __restrict__ galT,
                                            const float* __restrict__ garT,
                                            float* __restrict__ u,
                                            float* __restrict__ v) {
  const int t    = blockIdx.y;
  const int wid  = threadIdx.x >> 6;
  const int lane = threadIdx.x & 63;     // lane = n
  const int k0   = blockIdx.x * 16 + wid * 4;
  const float* gl = galT + (size_t)t * 512 * 64;
  const float* gr = garT + (size_t)t * 512 * 64;
  const float* Wb = W + ((size_t)t * 512 + k0) * 512;
  float au[4] = {}, av[4] = {};
  for (int d = 0; d < 512; ++d) {
    float g1 = gl[d * 64 + lane];
    float g2 = gr[d * 64 + lane];
#pragma unroll
    for (int kk = 0; kk < 4; ++kk) {
      float w = Wb[(size_t)kk * 512 + d];
      au[kk] = fmaf(w, g1, au[kk]);
      av[kk] = fmaf(w, g2, av[kk]);
    }
  }
#pragma unroll
  for (int kk = 0; kk < 4; ++kk) {
    u[((size_t)t * 64 + lane) * 512 + k0 + kk] = au[kk];
    v[((size_t)t * 64 + lane) * 512 + k0 + kk] = av[kk];
  }
}

// ---------- 4. left/right ----------
__global__ __launch_bounds__(256) void k_lr(const float* __restrict__ x,
                                            const float* __restrict__ u,
                                            const float* __restrict__ v,
                                            float* __restrict__ left,
                                            float* __restrict__ right) {
  const int n = blockIdx.y;
  const int itile = blockIdx.x;
  const int tid = threadIdx.x;
  const int wid = tid >> 6, lane = tid & 63;
  __shared__ float us[3][8][64], vs[3][8][64];
  for (int idx = tid; idx < 3 * 512; idx += 256) {
    int t = idx >> 9, k = idx & 511;
    us[t][k & 7][k >> 3] = u[((size_t)t * 64 + n) * 512 + k];
    vs[t][k & 7][k >> 3] = v[((size_t)t * 64 + n) * 512 + k];
  }
  __syncthreads();
  for (int ii = 0; ii < 16; ++ii) {
    int i = itile * 64 + wid * 16 + ii;
    const float4* row = (const float4*)(x + ((size_t)n * 512 + i) * 512) + lane * 2;
    float4 f0 = row[0], f1 = row[1];
    float xe[8] = {f0.x, f0.y, f0.z, f0.w, f1.x, f1.y, f1.z, f1.w};
    float pl[3] = {}, pr[3] = {};
#pragma unroll
    for (int t = 0; t < 3; ++t) {
#pragma unroll
      for (int e = 0; e < 8; ++e) {
        pl[t] = fmaf(xe[e], us[t][e][lane], pl[t]);
        pr[t] = fmaf(xe[e], vs[t][e][lane], pr[t]);
      }
    }
#pragma unroll
    for (int t = 0; t < 3; ++t) {
      for (int off = 32; off > 0; off >>= 1) {
        pl[t] += __shfl_xor(pl[t], off);
        pr[t] += __shfl_xor(pr[t], off);
      }
    }
    if (lane == 0) {
#pragma unroll
      for (int t = 0; t < 3; ++t) {
        left [((size_t)t * 64 + n) * 512 + i] = pl[t];
        right[((size_t)t * 64 + n) * 512 + i] = pr[t];
      }
    }
  }
}

// ---------- 5. MFMA GEMM1: h2T[n][d][i] = (X[n] @ W2)^T  (bf16 in, bf16 out) ----------
__global__ __launch_bounds__(256) void k_gemm1(const unsigned short* __restrict__ X,
                                               const unsigned short* __restrict__ WT,
                                               unsigned short* __restrict__ h2T) {
  const int n  = blockIdx.y;
  const int i0 = (blockIdx.x >> 2) * 128;
  const int d0 = (blockIdx.x & 3) * 128;
  const int tid = threadIdx.x;
  const int lane = tid & 63, w = tid >> 6;
  const int wm = w >> 1, wn = w & 1;
  __shared__ __attribute__((aligned(16))) char As[8192];
  __shared__ __attribute__((aligned(16))) char Bs[8192];
  const int srow = tid >> 2;
  const int kbp  = tid & 3;
  f32x4 acc[4][4];
#pragma unroll
  for (int a = 0; a < 4; ++a)
#pragma unroll
    for (int b = 0; b < 4; ++b) acc[a][b] = (f32x4){0.f, 0.f, 0.f, 0.f};

  const size_t xbase = (size_t)n * 262144;
  int ra[4], rb[4];
#pragma unroll
  for (int f = 0; f < 4; ++f) {
    int row = wm * 64 + f * 16 + (lane & 15);
    ra[f] = row * 64 + (((lane >> 4) ^ ((row >> 1) & 3)) << 4);
    int rowb = wn * 64 + f * 16 + (lane & 15);
    rb[f] = rowb * 64 + (((lane >> 4) ^ ((rowb >> 1) & 3)) << 4);
  }
  // staging: physical chunk kbp of row holds logical chunk kbp ^ ((row>>1)&3)
  const int kl0 = (kbp ^ ((srow >> 1) & 3)) * 8;          // row = srow
  const int kl1 = (kbp ^ (((64 + srow) >> 1) & 3)) * 8;   // row = 64+srow

  for (int kc = 0; kc < 512; kc += 32) {
    __syncthreads();
    GLOAD16(X + xbase + (size_t)(i0 + srow) * 512 + kc + kl0,       As + tid * 16);
    GLOAD16(X + xbase + (size_t)(i0 + 64 + srow) * 512 + kc + kl1,  As + 4096 + tid * 16);
    GLOAD16(WT + (size_t)(d0 + srow) * 512 + kc + kl0,              Bs + tid * 16);
    GLOAD16(WT + (size_t)(d0 + 64 + srow) * 512 + kc + kl1,         Bs + 4096 + tid * 16);
    __syncthreads();
    short8 a[4], b[4];
#pragma unroll
    for (int f = 0; f < 4; ++f) a[f] = *(const short8*)(As + ra[f]);
#pragma unroll
    for (int f = 0; f < 4; ++f) b[f] = *(const short8*)(Bs + rb[f]);
#pragma unroll
    for (int mf = 0; mf < 4; ++mf)
#pragma unroll
      for (int nf = 0; nf < 4; ++nf)
        acc[mf][nf] = __builtin_amdgcn_mfma_f32_16x16x32_bf16(a[mf], b[nf], acc[mf][nf], 0, 0, 0);
  }
  const int ib = i0 + wm * 64 + (lane >> 4) * 4;
  const int db = d0 + wn * 64 + (lane & 15);
#pragma unroll
  for (int mf = 0; mf < 4; ++mf)
#pragma unroll
    for (int nf = 0; nf < 4; ++nf) {
      f32x4 vv = acc[mf][nf];
      ushort4 pk;
      pk.x = f2bf(vv.x); pk.y = f2bf(vv.y); pk.z = f2bf(vv.z); pk.w = f2bf(vv.w);
      *(ushort4*)&h2T[xbase + (size_t)(db + nf * 16) * 512 + ib + mf * 16] = pk;
    }
}

// ---------- 6. masked softmax -> coefs bf16 [n][i][j] ----------
__global__ __launch_bounds__(256) void k_softmax(const int* __restrict__ adj,
                                                 const float* __restrict__ left,
                                                 const float* __restrict__ right,
                                                 unsigned short* __restrict__ coefs) {
  const int n = blockIdx.y;
  const int wid = threadIdx.x >> 6, lane = threadIdx.x & 63;
  const int i = blockIdx.x * 4 + wid;
  __shared__ float rights[3][8][64];
  for (int idx = threadIdx.x; idx < 3 * 512; idx += 256) {
    int t = idx >> 9, j = idx & 511;
    rights[t][j & 7][j >> 3] = right[((size_t)t * 64 + n) * 512 + j];
  }
  __syncthreads();
  float l0 = left[((size_t)0 * 64 + n) * 512 + i];
  float l1 = left[((size_t)1 * 64 + n) * 512 + i];
  float l2 = left[((size_t)2 * 64 + n) * 512 + i];
  const int4* ap = (const int4*)(adj + ((size_t)n * 512 + i) * 512) + lane * 2;
  int4 a0 = ap[0], a1 = ap[1];
  int av[8] = {a0.x, a0.y, a0.z, a0.w, a1.x, a1.y, a1.z, a1.w};
  float s[8];
#pragma unroll
  for (int e = 0; e < 8; ++e) {
    int tv = av[e];
    if (tv == 0) s[e] = -9e15f;
    else {
      float lv = (tv == 1) ? l0 : (tv == 2) ? l1 : l2;
      float xv = lv + rights[tv - 1][e][lane];
      s[e] = (xv >= 0.f) ? xv : 0.2f * xv;
    }
  }
  float m = s[0];
#pragma unroll
  for (int e = 1; e < 8; ++e) m = fmaxf(m, s[e]);
  for (int off = 32; off > 0; off >>= 1) m = fmaxf(m, __shfl_xor(m, off));
  float p[8], sum = 0.f;
#pragma unroll
  for (int e = 0; e < 8; ++e) { p[e] = __expf(s[e] - m); sum += p[e]; }
  for (int off = 32; off > 0; off >>= 1) sum += __shfl_xor(sum, off);
  float inv = 1.f / sum;
  uint4 o;
  o.x = ((unsigned)f2bf(p[1] * inv) << 16) | f2bf(p[0] * inv);
  o.y = ((unsigned)f2bf(p[3] * inv) << 16) | f2bf(p[2] * inv);
  o.z = ((unsigned)f2bf(p[5] * inv) << 16) | f2bf(p[4] * inv);
  o.w = ((unsigned)f2bf(p[7] * inv) << 16) | f2bf(p[6] * inv);
  *(uint4*)(coefs + ((size_t)n * 512 + i) * 512 + lane * 8) = o;
}

// ---------- 7. transpose coefs[n][i][j] -> coefsT[n][j][i] (bf16) ----------
__global__ __launch_bounds__(256) void k_tr(const unsigned short* __restrict__ c,
                                            unsigned short* __restrict__ ct) {
  __shared__ __attribute__((aligned(16))) unsigned short t[64][72];
  const int n = blockIdx.z, i0 = blockIdx.y * 64, j0 = blockIdx.x * 64;
  const size_t base = (size_t)n * 262144;
  for (int idx = threadIdx.x; idx < 512; idx += 256) {
    int r = idx >> 3, cc = (idx & 7) * 8;
    *(uint4*)&t[r][cc] = *(const uint4*)&c[base + (size_t)(i0 + r) * 512 + j0 + cc];
  }
  __syncthreads();
  for (int idx = threadIdx.x; idx < 512; idx += 256) {
    int r = idx >> 3, cc = (idx & 7) * 8;   // r = j-local
    ushort4 o0, o1;
    o0.x = t[cc + 0][r]; o0.y = t[cc + 1][r]; o0.z = t[cc + 2][r]; o0.w = t[cc + 3][r];
    o1.x = t[cc + 4][r]; o1.y = t[cc + 5][r]; o1.z = t[cc + 6][r]; o1.w = t[cc + 7][r];
    *(ushort4*)&ct[base + (size_t)(j0 + r) * 512 + i0 + cc]     = o0;
    *(ushort4*)&ct[base + (size_t)(j0 + r) * 512 + i0 + cc + 4] = o1;
  }
}

// ---------- 8. MFMA GEMM2: out[n][j][d] = coefsT[n] @ h2T[n]^T (f32 out) ----------
__global__ __launch_bounds__(256) void k_gemm2(const unsigned short* __restrict__ CT,
                                               const unsigned short* __restrict__ H2T,
                                               float* __restrict__ out) {
  const int n  = blockIdx.y;
  const int j0 = (blockIdx.x >> 2) * 128;
  const int d0 = (blockIdx.x & 3) * 128;
  const int tid = threadIdx.x;
  const int lane = tid & 63, w = tid >> 6;
  const int wm = w >> 1, wn = w & 1;
  __shared__ __attribute__((aligned(16))) char As[8192];
  __shared__ __attribute__((aligned(16))) char Bs[8192];
  const int srow = tid >> 2;
  const int kbp  = tid & 3;
  f32x4 acc[4][4];
#pragma unroll
  for (int a = 0; a < 4; ++a)
#pragma unroll
    for (int b = 0; b < 4; ++b) acc[a][b] = (f32x4){0.f, 0.f, 0.f, 0.f};

  const size_t base = (size_t)n * 262144;
  int ra[4], rb[4];
#pragma unroll
  for (int f = 0; f < 4; ++f) {
    int row = wm * 64 + f * 16 + (lane & 15);
    ra[f] = row * 64 + (((lane >> 4) ^ ((row >> 1) & 3)) << 4);
    int rowb = wn * 64 + f * 16 + (lane & 15);
    rb[f] = rowb * 64 + (((lane >> 4) ^ ((rowb >> 1) & 3)) << 4);
  }
  const int kl0 = (kbp ^ ((srow >> 1) & 3)) * 8;
  const int kl1 = (kbp ^ (((64 + srow) >> 1) & 3)) * 8;

  for (int kc = 0; kc < 512; kc += 32) {
    __syncthreads();
    GLOAD16(CT + base + (size_t)(j0 + srow) * 512 + kc + kl0,       As + tid * 16);
    GLOAD16(CT + base + (size_t)(j0 + 64 + srow) * 512 + kc + kl1,  As + 4096 + tid * 16);
    GLOAD16(H2T + base + (size_t)(d0 + srow) * 512 + kc + kl0,      Bs + tid * 16);
    GLOAD16(H2T + base + (size_t)(d0 + 64 + srow) * 512 + kc + kl1, Bs + 4096 + tid * 16);
    __syncthreads();
    short8 a[4], b[4];
#pragma unroll
    for (int f = 0; f < 4; ++f) a[f] = *(const short8*)(As + ra[f]);
#pragma unroll
    for (int f = 0; f < 4; ++f) b[f] = *(const short8*)(Bs + rb[f]);
#pragma unroll
    for (int mf = 0; mf < 4; ++mf)
#pragma unroll
      for (int nf = 0; nf < 4; ++nf)
        acc[mf][nf] = __builtin_amdgcn_mfma_f32_16x16x32_bf16(a[mf], b[nf], acc[mf][nf], 0, 0, 0);
  }
  const int jb = j0 + wm * 64 + (lane >> 4) * 4;
  const int db = d0 + wn * 64 + (lane & 15);
#pragma unroll
  for (int mf = 0; mf < 4; ++mf)
#pragma unroll
    for (int nf = 0; nf < 4; ++nf) {
      f32x4 vv = acc[mf][nf];
      float* op = out + base + (size_t)(jb + mf * 16) * 512 + db + nf * 16;
      op[0]        = vv.x;
      op[512]      = vv.y;
      op[1024]     = vv.z;
      op[1536]     = vv.w;
    }
}

extern "C" void kernel_launch(void* const* d_in, const int* in_sizes, int n_in,
                              void* d_out, int out_size, void* d_ws, size_t ws_size,
                              hipStream_t stream) {
  const float* input  = (const float*)d_in[0];
  const int*   adj    = (const int*)d_in[1];
  const float* query  = (const float*)d_in[3];
  const float* W_type = (const float*)d_in[4];
  const float* a_type = (const float*)d_in[5];
  const float* W1     = (const float*)d_in[6];
  const float* W2     = (const float*)d_in[7];
  float* out = (float*)d_out;

  char* ws = (char*)d_ws;
  float* r     = (float*)(ws);                    //   786,432 B
  float* galT  = (float*)(ws + 786432);           //   393,216 B
  float* garT  = (float*)(ws + 1179648);          //   393,216 B
  float* u     = (float*)(ws + 1572864);          //   393,216 B
  float* v     = (float*)(ws + 1966080);          //   393,216 B
  float* left  = (float*)(ws + 2359296);          //   393,216 B
  float* right = (float*)(ws + 2752512);          //   393,216 B
  unsigned short* Xbf  = (unsigned short*)(ws + 3145728);    // 33,554,432 B (reused as coefsT)
  unsigned short* h2T  = (unsigned short*)(ws + 36700160);   // 33,554,432 B
  unsigned short* WT   = (unsigned short*)(ws + 70254592);   //    524,288 B
  // total ws use: 70,778,880 B
  unsigned short* coefs  = (unsigned short*)d_out;  // parked in d_out (33.5 MB <= 67 MB), dead before GEMM2 writes
  unsigned short* coefsT = Xbf;                     // Xbf dead after k_gemm1

  k_conv  <<<dim3(2048),       256, 0, stream>>>(input, Xbf, 4194304);
  k_wt    <<<dim3(8, 8),       256, 0, stream>>>(W_type + (size_t)2 * 262144, WT);
  k_qattn1<<<dim3(16, 2, 3),   256, 0, stream>>>(query, W1, r);
  k_qattn2<<<dim3(16, 2, 3),   256, 0, stream>>>(r, W2, a_type, galT, garT);
  k_uv    <<<dim3(32, 3),      256, 0, stream>>>(W_type, galT, garT, u, v);
  k_lr    <<<dim3(8, 64),      256, 0, stream>>>(input, u, v, left, right);
  k_gemm1 <<<dim3(16, 64),     256, 0, stream>>>(Xbf, WT, h2T);
  k_softmax<<<dim3(128, 64),   256, 0, stream>>>(adj, left, right, coefs);
  k_tr    <<<dim3(8, 8, 64),   256, 0, stream>>>(coefs, coefsT);
  k_gemm2 <<<dim3(16, 64),     256, 0, stream>>>(coefsT, h2T, out);
}

// Round 3
// 256.108 us; speedup vs baseline: 2.3862x; 1.2892x over previous
//
#include <hip/hip_runtime.h>
#include <cstdint>

typedef __attribute__((ext_vector_type(8))) short short8;
typedef __attribute__((ext_vector_type(4))) float f32x4;

// ---------- helpers ----------
__device__ __forceinline__ unsigned short f2bf(float x) {
  unsigned int u = __float_as_uint(x);
  u += 0x7FFFu + ((u >> 16) & 1u);   // round-to-nearest-even
  return (unsigned short)(u >> 16);
}
__device__ __forceinline__ float bf2f(unsigned int h) {
  return __uint_as_float(h << 16);
}

#define GLOAD16(gsrc, ldst)                                                        \
  __builtin_amdgcn_global_load_lds(                                                \
      (const __attribute__((address_space(1))) void*)(gsrc),                       \
      (__attribute__((address_space(3))) void*)(ldst), 16, 0, 0)

// ---------- 0b. WT[d][k] = bf16(W2[k][d]) ----------
__global__ __launch_bounds__(256) void k_wt(const float* __restrict__ W,
                                            unsigned short* __restrict__ WT) {
  __shared__ float t[64][68];
  const int k0 = blockIdx.y * 64, d0 = blockIdx.x * 64;
  for (int idx = threadIdx.x; idx < 4096; idx += 256) {
    int r = idx >> 6, c = idx & 63;
    t[r][c] = W[(size_t)(k0 + r) * 512 + d0 + c];
  }
  __syncthreads();
  for (int idx = threadIdx.x; idx < 4096; idx += 256) {
    int r = idx >> 6, c = idx & 63;     // r = d-local, c = k-local
    WT[(size_t)(d0 + r) * 512 + k0 + c] = f2bf(t[c][r]);
  }
}

// ---------- gate 1: rpart[t][kc][col][n] = partial (q @ W1[t]) ----------
// grid (16 col-tiles of 64, 4 K-chunks of 128, 3 types), 256 thr
__global__ __launch_bounds__(256) void k_gate1(const float* __restrict__ q,
                                               const float* __restrict__ W1,
                                               float* __restrict__ rpart) {
  const int c0 = blockIdx.x * 64;
  const int k0 = blockIdx.y * 128;
  const int t  = blockIdx.z;
  const int tid = threadIdx.x;
  const int lane = tid & 63;           // row n
  const int wcs = __builtin_amdgcn_readfirstlane(tid >> 6);
  __shared__ float qs[64][133];        // [n][k-local], stride 133 (5 mod 32)
  for (int idx = tid; idx < 2048; idx += 256) {
    int r = idx >> 5, c4 = (idx & 31) * 4;
    float4 f = *(const float4*)&q[(size_t)r * 512 + k0 + c4];
    qs[r][c4 + 0] = f.x; qs[r][c4 + 1] = f.y;
    qs[r][c4 + 2] = f.z; qs[r][c4 + 3] = f.w;
  }
  __syncthreads();
  const float* Wp = W1 + ((size_t)t * 512 + k0) * 1024 + c0 + wcs * 16;
  float acc[16] = {};
  for (int k = 0; k < 128; ++k) {
    float qr = qs[lane][k];
    const float* wr = Wp + (size_t)k * 1024;
    float4 w0 = *(const float4*)(wr);
    float4 w1 = *(const float4*)(wr + 4);
    float4 w2 = *(const float4*)(wr + 8);
    float4 w3 = *(const float4*)(wr + 12);
    acc[0]  = fmaf(qr, w0.x, acc[0]);  acc[1]  = fmaf(qr, w0.y, acc[1]);
    acc[2]  = fmaf(qr, w0.z, acc[2]);  acc[3]  = fmaf(qr, w0.w, acc[3]);
    acc[4]  = fmaf(qr, w1.x, acc[4]);  acc[5]  = fmaf(qr, w1.y, acc[5]);
    acc[6]  = fmaf(qr, w1.z, acc[6]);  acc[7]  = fmaf(qr, w1.w, acc[7]);
    acc[8]  = fmaf(qr, w2.x, acc[8]);  acc[9]  = fmaf(qr, w2.y, acc[9]);
    acc[10] = fmaf(qr, w2.z, acc[10]); acc[11] = fmaf(qr, w2.w, acc[11]);
    acc[12] = fmaf(qr, w3.x, acc[12]); acc[13] = fmaf(qr, w3.y, acc[13]);
    acc[14] = fmaf(qr, w3.z, acc[14]); acc[15] = fmaf(qr, w3.w, acc[15]);
  }
  float* rp = rpart + ((size_t)(t * 4 + blockIdx.y) * 1024 + c0 + wcs * 16) * 64 + lane;
#pragma unroll
  for (int cc = 0; cc < 16; ++cc) rp[(size_t)cc * 64] = acc[cc];
}

// ---------- gate 2: gpart[t][kc][col][n] = partial (relu(r) @ W2[t]) ----------
// grid (16 col-tiles of 64, 8 K-chunks of 128, 3 types), 256 thr
__global__ __launch_bounds__(256) void k_gate2(const float* __restrict__ rpart,
                                               const float* __restrict__ W2,
                                               float* __restrict__ gpart) {
  const int c0 = blockIdx.x * 64;
  const int k0 = blockIdx.y * 128;     // chunk of r's 1024 columns
  const int t  = blockIdx.z;
  const int tid = threadIdx.x;
  const int lane = tid & 63;
  const int wcs = __builtin_amdgcn_readfirstlane(tid >> 6);
  __shared__ float qs[64][133];
  // stage qs[n][kl] = relu(sum_kc1 rpart[t][kc1][k0+kl][n])
  for (int idx = tid; idx < 2048; idx += 256) {
    int kl = idx >> 4, n4 = (idx & 15) * 4;
    const float* rp = rpart + ((size_t)t * 4 * 1024 + k0 + kl) * 64 + n4;
    float4 a = *(const float4*)(rp);
    float4 b = *(const float4*)(rp + 65536);
    float4 c = *(const float4*)(rp + 131072);
    float4 d = *(const float4*)(rp + 196608);
    qs[n4 + 0][kl] = fmaxf(a.x + b.x + c.x + d.x, 0.f);
    qs[n4 + 1][kl] = fmaxf(a.y + b.y + c.y + d.y, 0.f);
    qs[n4 + 2][kl] = fmaxf(a.z + b.z + c.z + d.z, 0.f);
    qs[n4 + 3][kl] = fmaxf(a.w + b.w + c.w + d.w, 0.f);
  }
  __syncthreads();
  const float* Wp = W2 + ((size_t)t << 20) + (size_t)k0 * 1024 + c0 + wcs * 16;
  float acc[16] = {};
  for (int k = 0; k < 128; ++k) {
    float qr = qs[lane][k];
    const float* wr = Wp + (size_t)k * 1024;
    float4 w0 = *(const float4*)(wr);
    float4 w1 = *(const float4*)(wr + 4);
    float4 w2 = *(const float4*)(wr + 8);
    float4 w3 = *(const float4*)(wr + 12);
    acc[0]  = fmaf(qr, w0.x, acc[0]);  acc[1]  = fmaf(qr, w0.y, acc[1]);
    acc[2]  = fmaf(qr, w0.z, acc[2]);  acc[3]  = fmaf(qr, w0.w, acc[3]);
    acc[4]  = fmaf(qr, w1.x, acc[4]);  acc[5]  = fmaf(qr, w1.y, acc[5]);
    acc[6]  = fmaf(qr, w1.z, acc[6]);  acc[7]  = fmaf(qr, w1.w, acc[7]);
    acc[8]  = fmaf(qr, w2.x, acc[8]);  acc[9]  = fmaf(qr, w2.y, acc[9]);
    acc[10] = fmaf(qr, w2.z, acc[10]); acc[11] = fmaf(qr, w2.w, acc[11]);
    acc[12] = fmaf(qr, w3.x, acc[12]); acc[13] = fmaf(qr, w3.y, acc[13]);
    acc[14] = fmaf(qr, w3.z, acc[14]); acc[15] = fmaf(qr, w3.w, acc[15]);
  }
  float* gp = gpart + ((size_t)(t * 8 + blockIdx.y) * 1024 + c0 + wcs * 16) * 64 + lane;
#pragma unroll
  for (int cc = 0; cc < 16; ++cc) gp[(size_t)cc * 64] = acc[cc];
}

// ---------- gate fin: sigmoid(sum) * a -> galT/garT ----------
// grid (256, 3): mg = bx*4 + wid, n = lane
__global__ __launch_bounds__(256) void k_gate_fin(const float* __restrict__ gpart,
                                                  const float* __restrict__ a_type,
                                                  float* __restrict__ galT,
                                                  float* __restrict__ garT) {
  const int t = blockIdx.y;
  const int n = threadIdx.x & 63;
  const int mg = blockIdx.x * 4 + (threadIdx.x >> 6);
  float s = 0.f;
#pragma unroll
  for (int kc = 0; kc < 8; ++kc)
    s += gpart[((size_t)(t * 8 + kc) * 1024 + mg) * 64 + n];
  float g = 1.f / (1.f + __expf(-s));
  float ga = g * a_type[t * 1024 + mg];
  if (mg < 512) galT[((size_t)t * 512 + mg) * 64 + n] = ga;
  else          garT[((size_t)t * 512 + (mg - 512)) * 64 + n] = ga;
}

// ---------- 3. u,v ----------
__global__ __launch_bounds__(256) void k_uv(const float* __restrict__ W,
                                            const float* __restrict__ galT,
                                            const float* __restrict__ garT,
                                            float* __restrict__ u,
                                            float* __restrict__ v) {
  const int t    = blockIdx.y;
  const int wid  = threadIdx.x >> 6;
  const int lane = threadIdx.x & 63;     // lane = n
  const int k0   = blockIdx.x * 16 + wid * 4;
  const float* gl = galT + (size_t)t * 512 * 64;
  const float* gr = garT + (size_t)t * 512 * 64;
  const float* Wb = W + ((size_t)t * 512 + k0) * 512;
  float au[4] = {}, av[4] = {};
  for (int d = 0; d < 512; ++d) {
    float g1 = gl[d * 64 + lane];
    float g2 = gr[d * 64 + lane];
#pragma unroll
    for (int kk = 0; kk < 4; ++kk) {
      float w = Wb[(size_t)kk * 512 + d];
      au[kk] = fmaf(w, g1, au[kk]);
      av[kk] = fmaf(w, g2, av[kk]);
    }
  }
#pragma unroll
  for (int kk = 0; kk < 4; ++kk) {
    u[((size_t)t * 64 + lane) * 512 + k0 + kk] = au[kk];
    v[((size_t)t * 64 + lane) * 512 + k0 + kk] = av[kk];
  }
}

// ---------- 4. left/right + fused bf16 conversion of input ----------
__global__ __launch_bounds__(256) void k_lr(const float* __restrict__ x,
                                            const float* __restrict__ u,
                                            const float* __restrict__ v,
                                            float* __restrict__ left,
                                            float* __restrict__ right,
                                            unsigned short* __restrict__ Xbf) {
  const int n = blockIdx.y;
  const int itile = blockIdx.x;
  const int tid = threadIdx.x;
  const int wid = tid >> 6, lane = tid & 63;
  __shared__ float us[3][8][64], vs[3][8][64];
  for (int idx = tid; idx < 3 * 512; idx += 256) {
    int t = idx >> 9, k = idx & 511;
    us[t][k & 7][k >> 3] = u[((size_t)t * 64 + n) * 512 + k];
    vs[t][k & 7][k >> 3] = v[((size_t)t * 64 + n) * 512 + k];
  }
  __syncthreads();
  for (int ii = 0; ii < 16; ++ii) {
    int i = itile * 64 + wid * 16 + ii;
    const float4* row = (const float4*)(x + ((size_t)n * 512 + i) * 512) + lane * 2;
    float4 f0 = row[0], f1 = row[1];
    float xe[8] = {f0.x, f0.y, f0.z, f0.w, f1.x, f1.y, f1.z, f1.w};
    // fused f32 -> bf16 store of input
    uint4 pk;
    pk.x = ((unsigned)f2bf(xe[1]) << 16) | f2bf(xe[0]);
    pk.y = ((unsigned)f2bf(xe[3]) << 16) | f2bf(xe[2]);
    pk.z = ((unsigned)f2bf(xe[5]) << 16) | f2bf(xe[4]);
    pk.w = ((unsigned)f2bf(xe[7]) << 16) | f2bf(xe[6]);
    *(uint4*)&Xbf[((size_t)n * 512 + i) * 512 + lane * 8] = pk;
    float pl[3] = {}, pr[3] = {};
#pragma unroll
    for (int t = 0; t < 3; ++t) {
#pragma unroll
      for (int e = 0; e < 8; ++e) {
        pl[t] = fmaf(xe[e], us[t][e][lane], pl[t]);
        pr[t] = fmaf(xe[e], vs[t][e][lane], pr[t]);
      }
    }
#pragma unroll
    for (int t = 0; t < 3; ++t) {
      for (int off = 32; off > 0; off >>= 1) {
        pl[t] += __shfl_xor(pl[t], off);
        pr[t] += __shfl_xor(pr[t], off);
      }
    }
    if (lane == 0) {
#pragma unroll
      for (int t = 0; t < 3; ++t) {
        left [((size_t)t * 64 + n) * 512 + i] = pl[t];
        right[((size_t)t * 64 + n) * 512 + i] = pr[t];
      }
    }
  }
}

// ---------- 5. MFMA GEMM1: h2T[n][d][i] = (X[n] @ W2)^T  (bf16 in, bf16 out) ----------
__global__ __launch_bounds__(256) void k_gemm1(const unsigned short* __restrict__ X,
                                               const unsigned short* __restrict__ WT,
                                               unsigned short* __restrict__ h2T) {
  const int n  = blockIdx.y;
  const int i0 = (blockIdx.x >> 2) * 128;
  const int d0 = (blockIdx.x & 3) * 128;
  const int tid = threadIdx.x;
  const int lane = tid & 63, w = tid >> 6;
  const int wm = w >> 1, wn = w & 1;
  __shared__ __attribute__((aligned(16))) char As[8192];
  __shared__ __attribute__((aligned(16))) char Bs[8192];
  const int srow = tid >> 2;
  const int kbp  = tid & 3;
  f32x4 acc[4][4];
#pragma unroll
  for (int a = 0; a < 4; ++a)
#pragma unroll
    for (int b = 0; b < 4; ++b) acc[a][b] = (f32x4){0.f, 0.f, 0.f, 0.f};

  const size_t xbase = (size_t)n * 262144;
  int ra[4], rb[4];
#pragma unroll
  for (int f = 0; f < 4; ++f) {
    int row = wm * 64 + f * 16 + (lane & 15);
    ra[f] = row * 64 + (((lane >> 4) ^ ((row >> 1) & 3)) << 4);
    int rowb = wn * 64 + f * 16 + (lane & 15);
    rb[f] = rowb * 64 + (((lane >> 4) ^ ((rowb >> 1) & 3)) << 4);
  }
  const int kl0 = (kbp ^ ((srow >> 1) & 3)) * 8;
  const int kl1 = (kbp ^ (((64 + srow) >> 1) & 3)) * 8;

  for (int kc = 0; kc < 512; kc += 32) {
    __syncthreads();
    GLOAD16(X + xbase + (size_t)(i0 + srow) * 512 + kc + kl0,       As + tid * 16);
    GLOAD16(X + xbase + (size_t)(i0 + 64 + srow) * 512 + kc + kl1,  As + 4096 + tid * 16);
    GLOAD16(WT + (size_t)(d0 + srow) * 512 + kc + kl0,              Bs + tid * 16);
    GLOAD16(WT + (size_t)(d0 + 64 + srow) * 512 + kc + kl1,         Bs + 4096 + tid * 16);
    __syncthreads();
    short8 a[4], b[4];
#pragma unroll
    for (int f = 0; f < 4; ++f) a[f] = *(const short8*)(As + ra[f]);
#pragma unroll
    for (int f = 0; f < 4; ++f) b[f] = *(const short8*)(Bs + rb[f]);
#pragma unroll
    for (int mf = 0; mf < 4; ++mf)
#pragma unroll
      for (int nf = 0; nf < 4; ++nf)
        acc[mf][nf] = __builtin_amdgcn_mfma_f32_16x16x32_bf16(a[mf], b[nf], acc[mf][nf], 0, 0, 0);
  }
  const int ib = i0 + wm * 64 + (lane >> 4) * 4;
  const int db = d0 + wn * 64 + (lane & 15);
#pragma unroll
  for (int mf = 0; mf < 4; ++mf)
#pragma unroll
    for (int nf = 0; nf < 4; ++nf) {
      f32x4 vv = acc[mf][nf];
      ushort4 pk;
      pk.x = f2bf(vv.x); pk.y = f2bf(vv.y); pk.z = f2bf(vv.z); pk.w = f2bf(vv.w);
      *(ushort4*)&h2T[xbase + (size_t)(db + nf * 16) * 512 + ib + mf * 16] = pk;
    }
}

// ---------- 6. masked softmax -> coefs bf16 [n][i][j] ----------
__global__ __launch_bounds__(256) void k_softmax(const int* __restrict__ adj,
                                                 const float* __restrict__ left,
                                                 const float* __restrict__ right,
                                                 unsigned short* __restrict__ coefs) {
  const int n = blockIdx.y;
  const int wid = threadIdx.x >> 6, lane = threadIdx.x & 63;
  const int i = blockIdx.x * 4 + wid;
  __shared__ float rights[3][8][64];
  for (int idx = threadIdx.x; idx < 3 * 512; idx += 256) {
    int t = idx >> 9, j = idx & 511;
    rights[t][j & 7][j >> 3] = right[((size_t)t * 64 + n) * 512 + j];
  }
  __syncthreads();
  float l0 = left[((size_t)0 * 64 + n) * 512 + i];
  float l1 = left[((size_t)1 * 64 + n) * 512 + i];
  float l2 = left[((size_t)2 * 64 + n) * 512 + i];
  const int4* ap = (const int4*)(adj + ((size_t)n * 512 + i) * 512) + lane * 2;
  int4 a0 = ap[0], a1 = ap[1];
  int av[8] = {a0.x, a0.y, a0.z, a0.w, a1.x, a1.y, a1.z, a1.w};
  float s[8];
#pragma unroll
  for (int e = 0; e < 8; ++e) {
    int tv = av[e];
    if (tv == 0) s[e] = -9e15f;
    else {
      float lv = (tv == 1) ? l0 : (tv == 2) ? l1 : l2;
      float xv = lv + rights[tv - 1][e][lane];
      s[e] = (xv >= 0.f) ? xv : 0.2f * xv;
    }
  }
  float m = s[0];
#pragma unroll
  for (int e = 1; e < 8; ++e) m = fmaxf(m, s[e]);
  for (int off = 32; off > 0; off >>= 1) m = fmaxf(m, __shfl_xor(m, off));
  float p[8], sum = 0.f;
#pragma unroll
  for (int e = 0; e < 8; ++e) { p[e] = __expf(s[e] - m); sum += p[e]; }
  for (int off = 32; off > 0; off >>= 1) sum += __shfl_xor(sum, off);
  float inv = 1.f / sum;
  uint4 o;
  o.x = ((unsigned)f2bf(p[1] * inv) << 16) | f2bf(p[0] * inv);
  o.y = ((unsigned)f2bf(p[3] * inv) << 16) | f2bf(p[2] * inv);
  o.z = ((unsigned)f2bf(p[5] * inv) << 16) | f2bf(p[4] * inv);
  o.w = ((unsigned)f2bf(p[7] * inv) << 16) | f2bf(p[6] * inv);
  *(uint4*)(coefs + ((size_t)n * 512 + i) * 512 + lane * 8) = o;
}

// ---------- 7. transpose coefs[n][i][j] -> coefsT[n][j][i] (bf16) ----------
__global__ __launch_bounds__(256) void k_tr(const unsigned short* __restrict__ c,
                                            unsigned short* __restrict__ ct) {
  __shared__ __attribute__((aligned(16))) unsigned short t[64][72];
  const int n = blockIdx.z, i0 = blockIdx.y * 64, j0 = blockIdx.x * 64;
  const size_t base = (size_t)n * 262144;
  for (int idx = threadIdx.x; idx < 512; idx += 256) {
    int r = idx >> 3, cc = (idx & 7) * 8;
    *(uint4*)&t[r][cc] = *(const uint4*)&c[base + (size_t)(i0 + r) * 512 + j0 + cc];
  }
  __syncthreads();
  for (int idx = threadIdx.x; idx < 512; idx += 256) {
    int r = idx >> 3, cc = (idx & 7) * 8;   // r = j-local
    ushort4 o0, o1;
    o0.x = t[cc + 0][r]; o0.y = t[cc + 1][r]; o0.z = t[cc + 2][r]; o0.w = t[cc + 3][r];
    o1.x = t[cc + 4][r]; o1.y = t[cc + 5][r]; o1.z = t[cc + 6][r]; o1.w = t[cc + 7][r];
    *(ushort4*)&ct[base + (size_t)(j0 + r) * 512 + i0 + cc]     = o0;
    *(ushort4*)&ct[base + (size_t)(j0 + r) * 512 + i0 + cc + 4] = o1;
  }
}

// ---------- 8. MFMA GEMM2: out[n][j][d] = coefsT[n] @ h2T[n]^T (f32 out) ----------
__global__ __launch_bounds__(256) void k_gemm2(const unsigned short* __restrict__ CT,
                                               const unsigned short* __restrict__ H2T,
                                               float* __restrict__ out) {
  const int n  = blockIdx.y;
  const int j0 = (blockIdx.x >> 2) * 128;
  const int d0 = (blockIdx.x & 3) * 128;
  const int tid = threadIdx.x;
  const int lane = tid & 63, w = tid >> 6;
  const int wm = w >> 1, wn = w & 1;
  __shared__ __attribute__((aligned(16))) char As[8192];
  __shared__ __attribute__((aligned(16))) char Bs[8192];
  const int srow = tid >> 2;
  const int kbp  = tid & 3;
  f32x4 acc[4][4];
#pragma unroll
  for (int a = 0; a < 4; ++a)
#pragma unroll
    for (int b = 0; b < 4; ++b) acc[a][b] = (f32x4){0.f, 0.f, 0.f, 0.f};

  const size_t base = (size_t)n * 262144;
  int ra[4], rb[4];
#pragma unroll
  for (int f = 0; f < 4; ++f) {
    int row = wm * 64 + f * 16 + (lane & 15);
    ra[f] = row * 64 + (((lane >> 4) ^ ((row >> 1) & 3)) << 4);
    int rowb = wn * 64 + f * 16 + (lane & 15);
    rb[f] = rowb * 64 + (((lane >> 4) ^ ((rowb >> 1) & 3)) << 4);
  }
  const int kl0 = (kbp ^ ((srow >> 1) & 3)) * 8;
  const int kl1 = (kbp ^ (((64 + srow) >> 1) & 3)) * 8;

  for (int kc = 0; kc < 512; kc += 32) {
    __syncthreads();
    GLOAD16(CT + base + (size_t)(j0 + srow) * 512 + kc + kl0,       As + tid * 16);
    GLOAD16(CT + base + (size_t)(j0 + 64 + srow) * 512 + kc + kl1,  As + 4096 + tid * 16);
    GLOAD16(H2T + base + (size_t)(d0 + srow) * 512 + kc + kl0,      Bs + tid * 16);
    GLOAD16(H2T + base + (size_t)(d0 + 64 + srow) * 512 + kc + kl1, Bs + 4096 + tid * 16);
    __syncthreads();
    short8 a[4], b[4];
#pragma unroll
    for (int f = 0; f < 4; ++f) a[f] = *(const short8*)(As + ra[f]);
#pragma unroll
    for (int f = 0; f < 4; ++f) b[f] = *(const short8*)(Bs + rb[f]);
#pragma unroll
    for (int mf = 0; mf < 4; ++mf)
#pragma unroll
      for (int nf = 0; nf < 4; ++nf)
        acc[mf][nf] = __builtin_amdgcn_mfma_f32_16x16x32_bf16(a[mf], b[nf], acc[mf][nf], 0, 0, 0);
  }
  const int jb = j0 + wm * 64 + (lane >> 4) * 4;
  const int db = d0 + wn * 64 + (lane & 15);
#pragma unroll
  for (int mf = 0; mf < 4; ++mf)
#pragma unroll
    for (int nf = 0; nf < 4; ++nf) {
      f32x4 vv = acc[mf][nf];
      float* op = out + base + (size_t)(jb + mf * 16) * 512 + db + nf * 16;
      op[0]    = vv.x;
      op[512]  = vv.y;
      op[1024] = vv.z;
      op[1536] = vv.w;
    }
}

extern "C" void kernel_launch(void* const* d_in, const int* in_sizes, int n_in,
                              void* d_out, int out_size, void* d_ws, size_t ws_size,
                              hipStream_t stream) {
  const float* input  = (const float*)d_in[0];
  const int*   adj    = (const int*)d_in[1];
  const float* query  = (const float*)d_in[3];
  const float* W_type = (const float*)d_in[4];
  const float* a_type = (const float*)d_in[5];
  const float* W1     = (const float*)d_in[6];
  const float* W2     = (const float*)d_in[7];
  float* out = (float*)d_out;

  char* ws = (char*)d_ws;
  float* galT  = (float*)(ws);                    //  393,216 B
  float* garT  = (float*)(ws + 393216);           //  393,216 B
  float* u     = (float*)(ws + 786432);           //  393,216 B
  float* v     = (float*)(ws + 1179648);          //  393,216 B
  float* left  = (float*)(ws + 1572864);          //  393,216 B
  float* right = (float*)(ws + 1966080);          //  393,216 B
  unsigned short* Xbf = (unsigned short*)(ws + 2359296);    // 33,554,432 B (reused as coefsT)
  unsigned short* h2T = (unsigned short*)(ws + 35913728);   // 33,554,432 B
  // rpart/gpart alias h2T's region: both dead before k_gemm1 writes h2T
  float* rpart = (float*)(ws + 35913728);                   //  3,145,728 B
  float* gpart = (float*)(ws + 39059456);                   //  6,291,456 B
  unsigned short* WT  = (unsigned short*)(ws + 69468160);   //    524,288 B
  // total ws use: 69,992,448 B
  unsigned short* coefs  = (unsigned short*)d_out;  // parked in d_out, dead before GEMM2 writes
  unsigned short* coefsT = Xbf;                     // Xbf dead after k_gemm1

  k_wt      <<<dim3(8, 8),      256, 0, stream>>>(W_type + (size_t)2 * 262144, WT);
  k_gate1   <<<dim3(16, 4, 3),  256, 0, stream>>>(query, W1, rpart);
  k_gate2   <<<dim3(16, 8, 3),  256, 0, stream>>>(rpart, W2, gpart);
  k_gate_fin<<<dim3(256, 3),    256, 0, stream>>>(gpart, a_type, galT, garT);
  k_uv      <<<dim3(32, 3),     256, 0, stream>>>(W_type, galT, garT, u, v);
  k_lr      <<<dim3(8, 64),     256, 0, stream>>>(input, u, v, left, right, Xbf);
  k_gemm1   <<<dim3(16, 64),    256, 0, stream>>>(Xbf, WT, h2T);
  k_softmax <<<dim3(128, 64),   256, 0, stream>>>(adj, left, right, coefs);
  k_tr      <<<dim3(8, 8, 64),  256, 0, stream>>>(coefs, coefsT);
  k_gemm2   <<<dim3(16, 64),    256, 0, stream>>>(coefsT, h2T, out);
}

// Round 4
// 227.700 us; speedup vs baseline: 2.6839x; 1.1248x over previous
//
#include <hip/hip_runtime.h>
#include <cstdint>

typedef __attribute__((ext_vector_type(8))) short short8;
typedef __attribute__((ext_vector_type(4))) float f32x4;

// ---------- helpers ----------
__device__ __forceinline__ unsigned short f2bf(float x) {
  unsigned int u = __float_as_uint(x);
  u += 0x7FFFu + ((u >> 16) & 1u);   // round-to-nearest-even
  return (unsigned short)(u >> 16);
}
__device__ __forceinline__ float bf2f(unsigned int h) {
  return __uint_as_float(h << 16);
}

#define GLOAD16(gsrc, ldst)                                                        \
  __builtin_amdgcn_global_load_lds(                                                \
      (const __attribute__((address_space(1))) void*)(gsrc),                       \
      (__attribute__((address_space(3))) void*)(ldst), 16, 0, 0)

// ---------- 0b. WT[d][k] = bf16(W2[k][d]) ----------
__global__ __launch_bounds__(256) void k_wt(const float* __restrict__ W,
                                            unsigned short* __restrict__ WT) {
  __shared__ float t[64][68];
  const int k0 = blockIdx.y * 64, d0 = blockIdx.x * 64;
  for (int idx = threadIdx.x; idx < 4096; idx += 256) {
    int r = idx >> 6, c = idx & 63;
    t[r][c] = W[(size_t)(k0 + r) * 512 + d0 + c];
  }
  __syncthreads();
  for (int idx = threadIdx.x; idx < 4096; idx += 256) {
    int r = idx >> 6, c = idx & 63;     // r = d-local, c = k-local
    WT[(size_t)(d0 + r) * 512 + k0 + c] = f2bf(t[c][r]);
  }
}

// ---------- gate 1: rpart[t][kc][col][n] = partial (q @ W1[t]) ----------
__global__ __launch_bounds__(256) void k_gate1(const float* __restrict__ q,
                                               const float* __restrict__ W1,
                                               float* __restrict__ rpart) {
  const int c0 = blockIdx.x * 64;
  const int k0 = blockIdx.y * 128;
  const int t  = blockIdx.z;
  const int tid = threadIdx.x;
  const int lane = tid & 63;           // row n
  const int wcs = __builtin_amdgcn_readfirstlane(tid >> 6);
  __shared__ float qs[64][133];
  for (int idx = tid; idx < 2048; idx += 256) {
    int r = idx >> 5, c4 = (idx & 31) * 4;
    float4 f = *(const float4*)&q[(size_t)r * 512 + k0 + c4];
    qs[r][c4 + 0] = f.x; qs[r][c4 + 1] = f.y;
    qs[r][c4 + 2] = f.z; qs[r][c4 + 3] = f.w;
  }
  __syncthreads();
  const float* Wp = W1 + ((size_t)t * 512 + k0) * 1024 + c0 + wcs * 16;
  float acc[16] = {};
  for (int k = 0; k < 128; ++k) {
    float qr = qs[lane][k];
    const float* wr = Wp + (size_t)k * 1024;
    float4 w0 = *(const float4*)(wr);
    float4 w1 = *(const float4*)(wr + 4);
    float4 w2 = *(const float4*)(wr + 8);
    float4 w3 = *(const float4*)(wr + 12);
    acc[0]  = fmaf(qr, w0.x, acc[0]);  acc[1]  = fmaf(qr, w0.y, acc[1]);
    acc[2]  = fmaf(qr, w0.z, acc[2]);  acc[3]  = fmaf(qr, w0.w, acc[3]);
    acc[4]  = fmaf(qr, w1.x, acc[4]);  acc[5]  = fmaf(qr, w1.y, acc[5]);
    acc[6]  = fmaf(qr, w1.z, acc[6]);  acc[7]  = fmaf(qr, w1.w, acc[7]);
    acc[8]  = fmaf(qr, w2.x, acc[8]);  acc[9]  = fmaf(qr, w2.y, acc[9]);
    acc[10] = fmaf(qr, w2.z, acc[10]); acc[11] = fmaf(qr, w2.w, acc[11]);
    acc[12] = fmaf(qr, w3.x, acc[12]); acc[13] = fmaf(qr, w3.y, acc[13]);
    acc[14] = fmaf(qr, w3.z, acc[14]); acc[15] = fmaf(qr, w3.w, acc[15]);
  }
  float* rp = rpart + ((size_t)(t * 4 + blockIdx.y) * 1024 + c0 + wcs * 16) * 64 + lane;
#pragma unroll
  for (int cc = 0; cc < 16; ++cc) rp[(size_t)cc * 64] = acc[cc];
}

// ---------- gate 2: gpart[t][kc][col][n] = partial (relu(r) @ W2[t]) ----------
__global__ __launch_bounds__(256) void k_gate2(const float* __restrict__ rpart,
                                               const float* __restrict__ W2,
                                               float* __restrict__ gpart) {
  const int c0 = blockIdx.x * 64;
  const int k0 = blockIdx.y * 128;
  const int t  = blockIdx.z;
  const int tid = threadIdx.x;
  const int lane = tid & 63;
  const int wcs = __builtin_amdgcn_readfirstlane(tid >> 6);
  __shared__ float qs[64][133];
  for (int idx = tid; idx < 2048; idx += 256) {
    int kl = idx >> 4, n4 = (idx & 15) * 4;
    const float* rp = rpart + ((size_t)t * 4 * 1024 + k0 + kl) * 64 + n4;
    float4 a = *(const float4*)(rp);
    float4 b = *(const float4*)(rp + 65536);
    float4 c = *(const float4*)(rp + 131072);
    float4 d = *(const float4*)(rp + 196608);
    qs[n4 + 0][kl] = fmaxf(a.x + b.x + c.x + d.x, 0.f);
    qs[n4 + 1][kl] = fmaxf(a.y + b.y + c.y + d.y, 0.f);
    qs[n4 + 2][kl] = fmaxf(a.z + b.z + c.z + d.z, 0.f);
    qs[n4 + 3][kl] = fmaxf(a.w + b.w + c.w + d.w, 0.f);
  }
  __syncthreads();
  const float* Wp = W2 + ((size_t)t << 20) + (size_t)k0 * 1024 + c0 + wcs * 16;
  float acc[16] = {};
  for (int k = 0; k < 128; ++k) {
    float qr = qs[lane][k];
    const float* wr = Wp + (size_t)k * 1024;
    float4 w0 = *(const float4*)(wr);
    float4 w1 = *(const float4*)(wr + 4);
    float4 w2 = *(const float4*)(wr + 8);
    float4 w3 = *(const float4*)(wr + 12);
    acc[0]  = fmaf(qr, w0.x, acc[0]);  acc[1]  = fmaf(qr, w0.y, acc[1]);
    acc[2]  = fmaf(qr, w0.z, acc[2]);  acc[3]  = fmaf(qr, w0.w, acc[3]);
    acc[4]  = fmaf(qr, w1.x, acc[4]);  acc[5]  = fmaf(qr, w1.y, acc[5]);
    acc[6]  = fmaf(qr, w1.z, acc[6]);  acc[7]  = fmaf(qr, w1.w, acc[7]);
    acc[8]  = fmaf(qr, w2.x, acc[8]);  acc[9]  = fmaf(qr, w2.y, acc[9]);
    acc[10] = fmaf(qr, w2.z, acc[10]); acc[11] = fmaf(qr, w2.w, acc[11]);
    acc[12] = fmaf(qr, w3.x, acc[12]); acc[13] = fmaf(qr, w3.y, acc[13]);
    acc[14] = fmaf(qr, w3.z, acc[14]); acc[15] = fmaf(qr, w3.w, acc[15]);
  }
  float* gp = gpart + ((size_t)(t * 8 + blockIdx.y) * 1024 + c0 + wcs * 16) * 64 + lane;
#pragma unroll
  for (int cc = 0; cc < 16; ++cc) gp[(size_t)cc * 64] = acc[cc];
}

// ---------- gate fin: sigmoid(sum) * a -> galT/garT ----------
__global__ __launch_bounds__(256) void k_gate_fin(const float* __restrict__ gpart,
                                                  const float* __restrict__ a_type,
                                                  float* __restrict__ galT,
                                                  float* __restrict__ garT) {
  const int t = blockIdx.y;
  const int n = threadIdx.x & 63;
  const int mg = blockIdx.x * 4 + (threadIdx.x >> 6);
  float s = 0.f;
#pragma unroll
  for (int kc = 0; kc < 8; ++kc)
    s += gpart[((size_t)(t * 8 + kc) * 1024 + mg) * 64 + n];
  float g = 1.f / (1.f + __expf(-s));
  float ga = g * a_type[t * 1024 + mg];
  if (mg < 512) galT[((size_t)t * 512 + mg) * 64 + n] = ga;
  else          garT[((size_t)t * 512 + (mg - 512)) * 64 + n] = ga;
}

// ---------- 3. u,v split-d partials ----------
// grid (8 k-tiles of 64, 8 d-chunks of 64, 3 types), 256 thr
// upart[t][dc][n][k] += sum over d-chunk of W[t][k][d]*gal[t][n][d]
__global__ __launch_bounds__(256) void k_uvp(const float* __restrict__ W,
                                             const float* __restrict__ galT,
                                             const float* __restrict__ garT,
                                             float* __restrict__ upart,
                                             float* __restrict__ vpart) {
  const int k0 = blockIdx.x * 64;
  const int d0 = blockIdx.y * 64;
  const int t  = blockIdx.z;
  const int tid = threadIdx.x;
  const int lane = tid & 63;           // lane = n
  const int wk = (tid >> 6) * 16;      // wave's k-subtile
  __shared__ float gal_s[64][64];      // [d][n]
  __shared__ float gar_s[64][64];
  __shared__ float W_s[64][64];        // [k][d]
  for (int idx = tid; idx < 1024; idx += 256) {
    int d = idx >> 4, n4 = (idx & 15) * 4;
    *(float4*)&gal_s[d][n4] = *(const float4*)&galT[((size_t)t * 512 + d0 + d) * 64 + n4];
    *(float4*)&gar_s[d][n4] = *(const float4*)&garT[((size_t)t * 512 + d0 + d) * 64 + n4];
    int k = idx >> 4, d4 = (idx & 15) * 4;
    *(float4*)&W_s[k][d4] = *(const float4*)&W[((size_t)t * 512 + k0 + k) * 512 + d0 + d4];
  }
  __syncthreads();
  float au[16] = {}, av[16] = {};
  for (int dq = 0; dq < 64; dq += 4) {
    float g1[4], g2[4];
#pragma unroll
    for (int e = 0; e < 4; ++e) { g1[e] = gal_s[dq + e][lane]; g2[e] = gar_s[dq + e][lane]; }
#pragma unroll
    for (int kk = 0; kk < 16; ++kk) {
      float4 wv = *(const float4*)&W_s[wk + kk][dq];
      au[kk] = fmaf(wv.x, g1[0], fmaf(wv.y, g1[1], fmaf(wv.z, g1[2], fmaf(wv.w, g1[3], au[kk]))));
      av[kk] = fmaf(wv.x, g2[0], fmaf(wv.y, g2[1], fmaf(wv.z, g2[2], fmaf(wv.w, g2[3], av[kk]))));
    }
  }
  const size_t ob = ((size_t)((t * 8 + blockIdx.y) * 64 + lane)) * 512 + k0 + wk;
#pragma unroll
  for (int q = 0; q < 4; ++q) {
    *(float4*)&upart[ob + q * 4] = make_float4(au[q*4], au[q*4+1], au[q*4+2], au[q*4+3]);
    *(float4*)&vpart[ob + q * 4] = make_float4(av[q*4], av[q*4+1], av[q*4+2], av[q*4+3]);
  }
}

// ---------- 4. left/right + fused bf16 conversion; sums uv partials ----------
__global__ __launch_bounds__(256) void k_lr(const float* __restrict__ x,
                                            const float* __restrict__ upart,
                                            const float* __restrict__ vpart,
                                            float* __restrict__ left,
                                            float* __restrict__ right,
                                            unsigned short* __restrict__ Xbf) {
  const int n = blockIdx.y;
  const int itile = blockIdx.x;
  const int tid = threadIdx.x;
  const int wid = tid >> 6, lane = tid & 63;
  __shared__ float us[3][8][64], vs[3][8][64];
  for (int idx = tid; idx < 3 * 512; idx += 256) {
    int t = idx >> 9, k = idx & 511;
    const float* up = upart + ((size_t)(t * 8) * 64 + n) * 512 + k;
    const float* vp = vpart + ((size_t)(t * 8) * 64 + n) * 512 + k;
    float su = 0.f, sv = 0.f;
#pragma unroll
    for (int dc = 0; dc < 8; ++dc) {
      su += up[(size_t)dc * 32768];
      sv += vp[(size_t)dc * 32768];
    }
    us[t][k & 7][k >> 3] = su;
    vs[t][k & 7][k >> 3] = sv;
  }
  __syncthreads();
  for (int ii = 0; ii < 16; ++ii) {
    int i = itile * 64 + wid * 16 + ii;
    const float4* row = (const float4*)(x + ((size_t)n * 512 + i) * 512) + lane * 2;
    float4 f0 = row[0], f1 = row[1];
    float xe[8] = {f0.x, f0.y, f0.z, f0.w, f1.x, f1.y, f1.z, f1.w};
    uint4 pk;
    pk.x = ((unsigned)f2bf(xe[1]) << 16) | f2bf(xe[0]);
    pk.y = ((unsigned)f2bf(xe[3]) << 16) | f2bf(xe[2]);
    pk.z = ((unsigned)f2bf(xe[5]) << 16) | f2bf(xe[4]);
    pk.w = ((unsigned)f2bf(xe[7]) << 16) | f2bf(xe[6]);
    *(uint4*)&Xbf[((size_t)n * 512 + i) * 512 + lane * 8] = pk;
    float pl[3] = {}, pr[3] = {};
#pragma unroll
    for (int t = 0; t < 3; ++t) {
#pragma unroll
      for (int e = 0; e < 8; ++e) {
        pl[t] = fmaf(xe[e], us[t][e][lane], pl[t]);
        pr[t] = fmaf(xe[e], vs[t][e][lane], pr[t]);
      }
    }
#pragma unroll
    for (int t = 0; t < 3; ++t) {
      for (int off = 32; off > 0; off >>= 1) {
        pl[t] += __shfl_xor(pl[t], off);
        pr[t] += __shfl_xor(pr[t], off);
      }
    }
    if (lane == 0) {
#pragma unroll
      for (int t = 0; t < 3; ++t) {
        left [((size_t)t * 64 + n) * 512 + i] = pl[t];
        right[((size_t)t * 64 + n) * 512 + i] = pr[t];
      }
    }
  }
}

// ---------- 5. MFMA GEMM1: h2T[n][d][i] = (X[n] @ W2)^T ----------
__global__ __launch_bounds__(256) void k_gemm1(const unsigned short* __restrict__ X,
                                               const unsigned short* __restrict__ WT,
                                               unsigned short* __restrict__ h2T) {
  const int n  = blockIdx.y;
  const int i0 = (blockIdx.x >> 2) * 128;
  const int d0 = (blockIdx.x & 3) * 128;
  const int tid = threadIdx.x;
  const int lane = tid & 63, w = tid >> 6;
  const int wm = w >> 1, wn = w & 1;
  __shared__ __attribute__((aligned(16))) char As[8192];
  __shared__ __attribute__((aligned(16))) char Bs[8192];
  const int srow = tid >> 2;
  const int kbp  = tid & 3;
  f32x4 acc[4][4];
#pragma unroll
  for (int a = 0; a < 4; ++a)
#pragma unroll
    for (int b = 0; b < 4; ++b) acc[a][b] = (f32x4){0.f, 0.f, 0.f, 0.f};

  const size_t xbase = (size_t)n * 262144;
  int ra[4], rb[4];
#pragma unroll
  for (int f = 0; f < 4; ++f) {
    int row = wm * 64 + f * 16 + (lane & 15);
    ra[f] = row * 64 + (((lane >> 4) ^ ((row >> 1) & 3)) << 4);
    int rowb = wn * 64 + f * 16 + (lane & 15);
    rb[f] = rowb * 64 + (((lane >> 4) ^ ((rowb >> 1) & 3)) << 4);
  }
  const int kl0 = (kbp ^ ((srow >> 1) & 3)) * 8;
  const int kl1 = (kbp ^ (((64 + srow) >> 1) & 3)) * 8;

  for (int kc = 0; kc < 512; kc += 32) {
    __syncthreads();
    GLOAD16(X + xbase + (size_t)(i0 + srow) * 512 + kc + kl0,       As + tid * 16);
    GLOAD16(X + xbase + (size_t)(i0 + 64 + srow) * 512 + kc + kl1,  As + 4096 + tid * 16);
    GLOAD16(WT + (size_t)(d0 + srow) * 512 + kc + kl0,              Bs + tid * 16);
    GLOAD16(WT + (size_t)(d0 + 64 + srow) * 512 + kc + kl1,         Bs + 4096 + tid * 16);
    __syncthreads();
    short8 a[4], b[4];
#pragma unroll
    for (int f = 0; f < 4; ++f) a[f] = *(const short8*)(As + ra[f]);
#pragma unroll
    for (int f = 0; f < 4; ++f) b[f] = *(const short8*)(Bs + rb[f]);
#pragma unroll
    for (int mf = 0; mf < 4; ++mf)
#pragma unroll
      for (int nf = 0; nf < 4; ++nf)
        acc[mf][nf] = __builtin_amdgcn_mfma_f32_16x16x32_bf16(a[mf], b[nf], acc[mf][nf], 0, 0, 0);
  }
  const int ib = i0 + wm * 64 + (lane >> 4) * 4;
  const int db = d0 + wn * 64 + (lane & 15);
#pragma unroll
  for (int mf = 0; mf < 4; ++mf)
#pragma unroll
    for (int nf = 0; nf < 4; ++nf) {
      f32x4 vv = acc[mf][nf];
      ushort4 pk;
      pk.x = f2bf(vv.x); pk.y = f2bf(vv.y); pk.z = f2bf(vv.z); pk.w = f2bf(vv.w);
      *(ushort4*)&h2T[xbase + (size_t)(db + nf * 16) * 512 + ib + mf * 16] = pk;
    }
}

// ---------- 6. masked softmax -> coefs bf16 [n][i][j] ----------
__global__ __launch_bounds__(256) void k_softmax(const int* __restrict__ adj,
                                                 const float* __restrict__ left,
                                                 const float* __restrict__ right,
                                                 unsigned short* __restrict__ coefs) {
  const int n = blockIdx.y;
  const int wid = threadIdx.x >> 6, lane = threadIdx.x & 63;
  const int i = blockIdx.x * 4 + wid;
  __shared__ float rights[3][8][64];
  for (int idx = threadIdx.x; idx < 3 * 512; idx += 256) {
    int t = idx >> 9, j = idx & 511;
    rights[t][j & 7][j >> 3] = right[((size_t)t * 64 + n) * 512 + j];
  }
  __syncthreads();
  float l0 = left[((size_t)0 * 64 + n) * 512 + i];
  float l1 = left[((size_t)1 * 64 + n) * 512 + i];
  float l2 = left[((size_t)2 * 64 + n) * 512 + i];
  const int4* ap = (const int4*)(adj + ((size_t)n * 512 + i) * 512) + lane * 2;
  int4 a0 = ap[0], a1 = ap[1];
  int av[8] = {a0.x, a0.y, a0.z, a0.w, a1.x, a1.y, a1.z, a1.w};
  float s[8];
#pragma unroll
  for (int e = 0; e < 8; ++e) {
    int tv = av[e];
    if (tv == 0) s[e] = -9e15f;
    else {
      float lv = (tv == 1) ? l0 : (tv == 2) ? l1 : l2;
      float xv = lv + rights[tv - 1][e][lane];
      s[e] = (xv >= 0.f) ? xv : 0.2f * xv;
    }
  }
  float m = s[0];
#pragma unroll
  for (int e = 1; e < 8; ++e) m = fmaxf(m, s[e]);
  for (int off = 32; off > 0; off >>= 1) m = fmaxf(m, __shfl_xor(m, off));
  float p[8], sum = 0.f;
#pragma unroll
  for (int e = 0; e < 8; ++e) { p[e] = __expf(s[e] - m); sum += p[e]; }
  for (int off = 32; off > 0; off >>= 1) sum += __shfl_xor(sum, off);
  float inv = 1.f / sum;
  uint4 o;
  o.x = ((unsigned)f2bf(p[1] * inv) << 16) | f2bf(p[0] * inv);
  o.y = ((unsigned)f2bf(p[3] * inv) << 16) | f2bf(p[2] * inv);
  o.z = ((unsigned)f2bf(p[5] * inv) << 16) | f2bf(p[4] * inv);
  o.w = ((unsigned)f2bf(p[7] * inv) << 16) | f2bf(p[6] * inv);
  *(uint4*)(coefs + ((size_t)n * 512 + i) * 512 + lane * 8) = o;
}

// ---------- 7. transpose coefs[n][i][j] -> coefsT[n][j][i] (bf16) ----------
__global__ __launch_bounds__(256) void k_tr(const unsigned short* __restrict__ c,
                                            unsigned short* __restrict__ ct) {
  __shared__ __attribute__((aligned(16))) unsigned short t[64][72];
  const int n = blockIdx.z, i0 = blockIdx.y * 64, j0 = blockIdx.x * 64;
  const size_t base = (size_t)n * 262144;
  for (int idx = threadIdx.x; idx < 512; idx += 256) {
    int r = idx >> 3, cc = (idx & 7) * 8;
    *(uint4*)&t[r][cc] = *(const uint4*)&c[base + (size_t)(i0 + r) * 512 + j0 + cc];
  }
  __syncthreads();
  for (int idx = threadIdx.x; idx < 512; idx += 256) {
    int r = idx >> 3, cc = (idx & 7) * 8;   // r = j-local
    ushort4 o0, o1;
    o0.x = t[cc + 0][r]; o0.y = t[cc + 1][r]; o0.z = t[cc + 2][r]; o0.w = t[cc + 3][r];
    o1.x = t[cc + 4][r]; o1.y = t[cc + 5][r]; o1.z = t[cc + 6][r]; o1.w = t[cc + 7][r];
    *(ushort4*)&ct[base + (size_t)(j0 + r) * 512 + i0 + cc]     = o0;
    *(ushort4*)&ct[base + (size_t)(j0 + r) * 512 + i0 + cc + 4] = o1;
  }
}

// ---------- 8. MFMA GEMM2: out[n][j][d] = coefsT[n] @ h2T[n]^T (f32 out) ----------
__global__ __launch_bounds__(256) void k_gemm2(const unsigned short* __restrict__ CT,
                                               const unsigned short* __restrict__ H2T,
                                               float* __restrict__ out) {
  const int n  = blockIdx.y;
  const int j0 = (blockIdx.x >> 2) * 128;
  const int d0 = (blockIdx.x & 3) * 128;
  const int tid = threadIdx.x;
  const int lane = tid & 63, w = tid >> 6;
  const int wm = w >> 1, wn = w & 1;
  __shared__ __attribute__((aligned(16))) char As[8192];
  __shared__ __attribute__((aligned(16))) char Bs[8192];
  const int srow = tid >> 2;
  const int kbp  = tid & 3;
  f32x4 acc[4][4];
#pragma unroll
  for (int a = 0; a < 4; ++a)
#pragma unroll
    for (int b = 0; b < 4; ++b) acc[a][b] = (f32x4){0.f, 0.f, 0.f, 0.f};

  const size_t base = (size_t)n * 262144;
  int ra[4], rb[4];
#pragma unroll
  for (int f = 0; f < 4; ++f) {
    int row = wm * 64 + f * 16 + (lane & 15);
    ra[f] = row * 64 + (((lane >> 4) ^ ((row >> 1) & 3)) << 4);
    int rowb = wn * 64 + f * 16 + (lane & 15);
    rb[f] = rowb * 64 + (((lane >> 4) ^ ((rowb >> 1) & 3)) << 4);
  }
  const int kl0 = (kbp ^ ((srow >> 1) & 3)) * 8;
  const int kl1 = (kbp ^ (((64 + srow) >> 1) & 3)) * 8;

  for (int kc = 0; kc < 512; kc += 32) {
    __syncthreads();
    GLOAD16(CT + base + (size_t)(j0 + srow) * 512 + kc + kl0,       As + tid * 16);
    GLOAD16(CT + base + (size_t)(j0 + 64 + srow) * 512 + kc + kl1,  As + 4096 + tid * 16);
    GLOAD16(H2T + base + (size_t)(d0 + srow) * 512 + kc + kl0,      Bs + tid * 16);
    GLOAD16(H2T + base + (size_t)(d0 + 64 + srow) * 512 + kc + kl1, Bs + 4096 + tid * 16);
    __syncthreads();
    short8 a[4], b[4];
#pragma unroll
    for (int f = 0; f < 4; ++f) a[f] = *(const short8*)(As + ra[f]);
#pragma unroll
    for (int f = 0; f < 4; ++f) b[f] = *(const short8*)(Bs + rb[f]);
#pragma unroll
    for (int mf = 0; mf < 4; ++mf)
#pragma unroll
      for (int nf = 0; nf < 4; ++nf)
        acc[mf][nf] = __builtin_amdgcn_mfma_f32_16x16x32_bf16(a[mf], b[nf], acc[mf][nf], 0, 0, 0);
  }
  const int jb = j0 + wm * 64 + (lane >> 4) * 4;
  const int db = d0 + wn * 64 + (lane & 15);
#pragma unroll
  for (int mf = 0; mf < 4; ++mf)
#pragma unroll
    for (int nf = 0; nf < 4; ++nf) {
      f32x4 vv = acc[mf][nf];
      float* op = out + base + (size_t)(jb + mf * 16) * 512 + db + nf * 16;
      op[0]    = vv.x;
      op[512]  = vv.y;
      op[1024] = vv.z;
      op[1536] = vv.w;
    }
}

extern "C" void kernel_launch(void* const* d_in, const int* in_sizes, int n_in,
                              void* d_out, int out_size, void* d_ws, size_t ws_size,
                              hipStream_t stream) {
  const float* input  = (const float*)d_in[0];
  const int*   adj    = (const int*)d_in[1];
  const float* query  = (const float*)d_in[3];
  const float* W_type = (const float*)d_in[4];
  const float* a_type = (const float*)d_in[5];
  const float* W1     = (const float*)d_in[6];
  const float* W2     = (const float*)d_in[7];
  float* out = (float*)d_out;

  char* ws = (char*)d_ws;
  float* galT  = (float*)(ws);                    //  393,216 B
  float* garT  = (float*)(ws + 393216);           //  393,216 B
  float* left  = (float*)(ws + 1572864);          //  393,216 B
  float* right = (float*)(ws + 1966080);          //  393,216 B
  unsigned short* Xbf = (unsigned short*)(ws + 2359296);    // 33,554,432 B (reused as coefsT)
  unsigned short* h2T = (unsigned short*)(ws + 35913728);   // 33,554,432 B
  // rpart/gpart/upart/vpart alias h2T's region: all dead before k_gemm1 writes h2T
  float* rpart = (float*)(ws + 35913728);                   //  3,145,728 B
  float* gpart = (float*)(ws + 39059456);                   //  6,291,456 B
  float* upart = (float*)(ws + 45350912);                   //  3,145,728 B
  float* vpart = (float*)(ws + 48496640);                   //  3,145,728 B
  unsigned short* WT  = (unsigned short*)(ws + 69468160);   //    524,288 B
  // total ws use: 69,992,448 B
  unsigned short* coefs  = (unsigned short*)d_out;  // parked in d_out, dead before GEMM2 writes
  unsigned short* coefsT = Xbf;                     // Xbf dead after k_gemm1

  k_wt      <<<dim3(8, 8),      256, 0, stream>>>(W_type + (size_t)2 * 262144, WT);
  k_gate1   <<<dim3(16, 4, 3),  256, 0, stream>>>(query, W1, rpart);
  k_gate2   <<<dim3(16, 8, 3),  256, 0, stream>>>(rpart, W2, gpart);
  k_gate_fin<<<dim3(256, 3),    256, 0, stream>>>(gpart, a_type, galT, garT);
  k_uvp     <<<dim3(8, 8, 3),   256, 0, stream>>>(W_type, galT, garT, upart, vpart);
  k_lr      <<<dim3(8, 64),     256, 0, stream>>>(input, upart, vpart, left, right, Xbf);
  k_gemm1   <<<dim3(16, 64),    256, 0, stream>>>(Xbf, WT, h2T);
  k_softmax <<<dim3(128, 64),   256, 0, stream>>>(adj, left, right, coefs);
  k_tr      <<<dim3(8, 8, 64),  256, 0, stream>>>(coefs, coefsT);
  k_gemm2   <<<dim3(16, 64),    256, 0, stream>>>(coefsT, h2T, out);
}

// Round 5
// 197.917 us; speedup vs baseline: 3.0878x; 1.1505x over previous
//
#include <hip/hip_runtime.h>
#include <cstdint>

typedef __attribute__((ext_vector_type(8))) short short8;
typedef __attribute__((ext_vector_type(4))) float f32x4;

// ---------- helpers ----------
__device__ __forceinline__ unsigned short f2bf(float x) {
  unsigned int u = __float_as_uint(x);
  u += 0x7FFFu + ((u >> 16) & 1u);   // round-to-nearest-even
  return (unsigned short)(u >> 16);
}

#define GLOAD16(gsrc, ldst)                                                        \
  __builtin_amdgcn_global_load_lds(                                                \
      (const __attribute__((address_space(1))) void*)(gsrc),                       \
      (__attribute__((address_space(3))) void*)(ldst), 16, 0, 0)

// ---------- 0b. WT[d][k] = bf16(W2[k][d]) ----------
__global__ __launch_bounds__(256) void k_wt(const float* __restrict__ W,
                                            unsigned short* __restrict__ WT) {
  __shared__ float t[64][68];
  const int k0 = blockIdx.y * 64, d0 = blockIdx.x * 64;
  for (int idx = threadIdx.x; idx < 4096; idx += 256) {
    int r = idx >> 6, c = idx & 63;
    t[r][c] = W[(size_t)(k0 + r) * 512 + d0 + c];
  }
  __syncthreads();
  for (int idx = threadIdx.x; idx < 4096; idx += 256) {
    int r = idx >> 6, c = idx & 63;     // r = d-local, c = k-local
    WT[(size_t)(d0 + r) * 512 + k0 + c] = f2bf(t[c][r]);
  }
}

// ---------- gate 1: rpart[t][kc][col][n] = partial (q @ W1[t]) ----------
__global__ __launch_bounds__(256) void k_gate1(const float* __restrict__ q,
                                               const float* __restrict__ W1,
                                               float* __restrict__ rpart) {
  const int c0 = blockIdx.x * 64;
  const int k0 = blockIdx.y * 128;
  const int t  = blockIdx.z;
  const int tid = threadIdx.x;
  const int lane = tid & 63;           // row n
  const int wcs = __builtin_amdgcn_readfirstlane(tid >> 6);
  __shared__ float qs[64][133];
  for (int idx = tid; idx < 2048; idx += 256) {
    int r = idx >> 5, c4 = (idx & 31) * 4;
    float4 f = *(const float4*)&q[(size_t)r * 512 + k0 + c4];
    qs[r][c4 + 0] = f.x; qs[r][c4 + 1] = f.y;
    qs[r][c4 + 2] = f.z; qs[r][c4 + 3] = f.w;
  }
  __syncthreads();
  const float* Wp = W1 + ((size_t)t * 512 + k0) * 1024 + c0 + wcs * 16;
  float acc[16] = {};
  for (int k = 0; k < 128; ++k) {
    float qr = qs[lane][k];
    const float* wr = Wp + (size_t)k * 1024;
    float4 w0 = *(const float4*)(wr);
    float4 w1 = *(const float4*)(wr + 4);
    float4 w2 = *(const float4*)(wr + 8);
    float4 w3 = *(const float4*)(wr + 12);
    acc[0]  = fmaf(qr, w0.x, acc[0]);  acc[1]  = fmaf(qr, w0.y, acc[1]);
    acc[2]  = fmaf(qr, w0.z, acc[2]);  acc[3]  = fmaf(qr, w0.w, acc[3]);
    acc[4]  = fmaf(qr, w1.x, acc[4]);  acc[5]  = fmaf(qr, w1.y, acc[5]);
    acc[6]  = fmaf(qr, w1.z, acc[6]);  acc[7]  = fmaf(qr, w1.w, acc[7]);
    acc[8]  = fmaf(qr, w2.x, acc[8]);  acc[9]  = fmaf(qr, w2.y, acc[9]);
    acc[10] = fmaf(qr, w2.z, acc[10]); acc[11] = fmaf(qr, w2.w, acc[11]);
    acc[12] = fmaf(qr, w3.x, acc[12]); acc[13] = fmaf(qr, w3.y, acc[13]);
    acc[14] = fmaf(qr, w3.z, acc[14]); acc[15] = fmaf(qr, w3.w, acc[15]);
  }
  float* rp = rpart + ((size_t)(t * 4 + blockIdx.y) * 1024 + c0 + wcs * 16) * 64 + lane;
#pragma unroll
  for (int cc = 0; cc < 16; ++cc) rp[(size_t)cc * 64] = acc[cc];
}

// ---------- gate 2: gpart[t][kc][col][n] = partial (relu(r) @ W2[t]) ----------
__global__ __launch_bounds__(256) void k_gate2(const float* __restrict__ rpart,
                                               const float* __restrict__ W2,
                                               float* __restrict__ gpart) {
  const int c0 = blockIdx.x * 64;
  const int k0 = blockIdx.y * 128;
  const int t  = blockIdx.z;
  const int tid = threadIdx.x;
  const int lane = tid & 63;
  const int wcs = __builtin_amdgcn_readfirstlane(tid >> 6);
  __shared__ float qs[64][133];
  for (int idx = tid; idx < 2048; idx += 256) {
    int kl = idx >> 4, n4 = (idx & 15) * 4;
    const float* rp = rpart + ((size_t)t * 4 * 1024 + k0 + kl) * 64 + n4;
    float4 a = *(const float4*)(rp);
    float4 b = *(const float4*)(rp + 65536);
    float4 c = *(const float4*)(rp + 131072);
    float4 d = *(const float4*)(rp + 196608);
    qs[n4 + 0][kl] = fmaxf(a.x + b.x + c.x + d.x, 0.f);
    qs[n4 + 1][kl] = fmaxf(a.y + b.y + c.y + d.y, 0.f);
    qs[n4 + 2][kl] = fmaxf(a.z + b.z + c.z + d.z, 0.f);
    qs[n4 + 3][kl] = fmaxf(a.w + b.w + c.w + d.w, 0.f);
  }
  __syncthreads();
  const float* Wp = W2 + ((size_t)t << 20) + (size_t)k0 * 1024 + c0 + wcs * 16;
  float acc[16] = {};
  for (int k = 0; k < 128; ++k) {
    float qr = qs[lane][k];
    const float* wr = Wp + (size_t)k * 1024;
    float4 w0 = *(const float4*)(wr);
    float4 w1 = *(const float4*)(wr + 4);
    float4 w2 = *(const float4*)(wr + 8);
    float4 w3 = *(const float4*)(wr + 12);
    acc[0]  = fmaf(qr, w0.x, acc[0]);  acc[1]  = fmaf(qr, w0.y, acc[1]);
    acc[2]  = fmaf(qr, w0.z, acc[2]);  acc[3]  = fmaf(qr, w0.w, acc[3]);
    acc[4]  = fmaf(qr, w1.x, acc[4]);  acc[5]  = fmaf(qr, w1.y, acc[5]);
    acc[6]  = fmaf(qr, w1.z, acc[6]);  acc[7]  = fmaf(qr, w1.w, acc[7]);
    acc[8]  = fmaf(qr, w2.x, acc[8]);  acc[9]  = fmaf(qr, w2.y, acc[9]);
    acc[10] = fmaf(qr, w2.z, acc[10]); acc[11] = fmaf(qr, w2.w, acc[11]);
    acc[12] = fmaf(qr, w3.x, acc[12]); acc[13] = fmaf(qr, w3.y, acc[13]);
    acc[14] = fmaf(qr, w3.z, acc[14]); acc[15] = fmaf(qr, w3.w, acc[15]);
  }
  float* gp = gpart + ((size_t)(t * 8 + blockIdx.y) * 1024 + c0 + wcs * 16) * 64 + lane;
#pragma unroll
  for (int cc = 0; cc < 16; ++cc) gp[(size_t)cc * 64] = acc[cc];
}

// ---------- gate fin: sigmoid(sum) * a -> galT/garT ----------
__global__ __launch_bounds__(256) void k_gate_fin(const float* __restrict__ gpart,
                                                  const float* __restrict__ a_type,
                                                  float* __restrict__ galT,
                                                  float* __restrict__ garT) {
  const int t = blockIdx.y;
  const int n = threadIdx.x & 63;
  const int mg = blockIdx.x * 4 + (threadIdx.x >> 6);
  float s = 0.f;
#pragma unroll
  for (int kc = 0; kc < 8; ++kc)
    s += gpart[((size_t)(t * 8 + kc) * 1024 + mg) * 64 + n];
  float g = 1.f / (1.f + __expf(-s));
  float ga = g * a_type[t * 1024 + mg];
  if (mg < 512) galT[((size_t)t * 512 + mg) * 64 + n] = ga;
  else          garT[((size_t)t * 512 + (mg - 512)) * 64 + n] = ga;
}

// ---------- 3. u,v split-d partials ----------
__global__ __launch_bounds__(256) void k_uvp(const float* __restrict__ W,
                                             const float* __restrict__ galT,
                                             const float* __restrict__ garT,
                                             float* __restrict__ upart,
                                             float* __restrict__ vpart) {
  const int k0 = blockIdx.x * 64;
  const int d0 = blockIdx.y * 64;
  const int t  = blockIdx.z;
  const int tid = threadIdx.x;
  const int lane = tid & 63;           // lane = n
  const int wk = (tid >> 6) * 16;      // wave's k-subtile
  __shared__ float gal_s[64][64];      // [d][n]
  __shared__ float gar_s[64][64];
  __shared__ float W_s[64][64];        // [k][d]
  for (int idx = tid; idx < 1024; idx += 256) {
    int d = idx >> 4, n4 = (idx & 15) * 4;
    *(float4*)&gal_s[d][n4] = *(const float4*)&galT[((size_t)t * 512 + d0 + d) * 64 + n4];
    *(float4*)&gar_s[d][n4] = *(const float4*)&garT[((size_t)t * 512 + d0 + d) * 64 + n4];
    int k = idx >> 4, d4 = (idx & 15) * 4;
    *(float4*)&W_s[k][d4] = *(const float4*)&W[((size_t)t * 512 + k0 + k) * 512 + d0 + d4];
  }
  __syncthreads();
  float au[16] = {}, av[16] = {};
  for (int dq = 0; dq < 64; dq += 4) {
    float g1[4], g2[4];
#pragma unroll
    for (int e = 0; e < 4; ++e) { g1[e] = gal_s[dq + e][lane]; g2[e] = gar_s[dq + e][lane]; }
#pragma unroll
    for (int kk = 0; kk < 16; ++kk) {
      float4 wv = *(const float4*)&W_s[wk + kk][dq];
      au[kk] = fmaf(wv.x, g1[0], fmaf(wv.y, g1[1], fmaf(wv.z, g1[2], fmaf(wv.w, g1[3], au[kk]))));
      av[kk] = fmaf(wv.x, g2[0], fmaf(wv.y, g2[1], fmaf(wv.z, g2[2], fmaf(wv.w, g2[3], av[kk]))));
    }
  }
  const size_t ob = ((size_t)((t * 8 + blockIdx.y) * 64 + lane)) * 512 + k0 + wk;
#pragma unroll
  for (int q = 0; q < 4; ++q) {
    *(float4*)&upart[ob + q * 4] = make_float4(au[q*4], au[q*4+1], au[q*4+2], au[q*4+3]);
    *(float4*)&vpart[ob + q * 4] = make_float4(av[q*4], av[q*4+1], av[q*4+2], av[q*4+3]);
  }
}

// ---------- 3b. sum uv partials -> uvbf[n][6][512] bf16 (cols 0..2=u(t), 3..5=v(t)) ----------
__global__ __launch_bounds__(256) void k_uvsum(const float* __restrict__ upart,
                                               const float* __restrict__ vpart,
                                               unsigned short* __restrict__ uvbf) {
  const int n = blockIdx.x;
  for (int idx = threadIdx.x; idx < 768; idx += 256) {
    int col = idx >> 7;              // 0..5
    int k4 = (idx & 127) * 4;
    const float* base = (col < 3)
        ? upart + ((size_t)(col * 8) * 64 + n) * 512 + k4
        : vpart + ((size_t)((col - 3) * 8) * 64 + n) * 512 + k4;
    float4 sv = {0.f, 0.f, 0.f, 0.f};
#pragma unroll
    for (int dc = 0; dc < 8; ++dc) {
      float4 t = *(const float4*)(base + (size_t)dc * 32768);
      sv.x += t.x; sv.y += t.y; sv.z += t.z; sv.w += t.w;
    }
    ushort4 o;
    o.x = f2bf(sv.x); o.y = f2bf(sv.y); o.z = f2bf(sv.z); o.w = f2bf(sv.w);
    *(ushort4*)&uvbf[((size_t)n * 6 + col) * 512 + k4] = o;
  }
}

// ---------- 4. k_lrm: single pass over X: f32->bf16 conversion + left/right via MFMA ----------
// grid (8 i-tiles of 64, 64 n), 256 thr / 4 waves (each wave = 16 rows)
__global__ __launch_bounds__(256) void k_lrm(const float* __restrict__ x,
                                             const unsigned short* __restrict__ uvbf,
                                             float* __restrict__ left,
                                             float* __restrict__ right,
                                             unsigned short* __restrict__ Xbf) {
  const int n  = blockIdx.y;
  const int i0 = blockIdx.x * 64;
  const int tid = threadIdx.x;
  const int lane = tid & 63, wid = tid >> 6;
  __shared__ unsigned short uvs[16][520];   // [col][k], pad->2-way max conflicts
  __shared__ __attribute__((aligned(16))) char As[4096];  // 64 rows x 32 k bf16, chunk-XOR

  // stage uv (cols 0..5 real; 6..15 zeros so MFMA B-frag reads are valid)
  for (int idx = tid; idx < 16 * 64; idx += 256) {
    int col = idx >> 6, k8 = (idx & 63) * 8;
    ushort4 z0 = {0, 0, 0, 0}, z1 = {0, 0, 0, 0};
    if (col < 6) {
      const unsigned short* p = uvbf + ((size_t)n * 6 + col) * 512 + k8;
      z0 = *(const ushort4*)p;
      z1 = *(const ushort4*)(p + 4);
    }
    *(ushort4*)&uvs[col][k8]     = z0;
    *(ushort4*)&uvs[col][k8 + 4] = z1;
  }
  const int row = tid >> 2, sub = tid & 3;
  const float* gp = x + ((size_t)n * 512 + i0 + row) * 512 + sub * 8;
  unsigned short* xp = Xbf + ((size_t)n * 512 + i0 + row) * 512 + sub * 8;
  const int lds_off = row * 64 + ((sub ^ (row & 3)) << 4);
  const int arow = wid * 16 + (lane & 15);
  const int a_off = arow * 64 + (((lane >> 4) ^ (arow & 3)) << 4);
  f32x4 acc = {0.f, 0.f, 0.f, 0.f};
  float4 f0 = *(const float4*)(gp);
  float4 f1 = *(const float4*)(gp + 4);
  __syncthreads();
  for (int s = 0; s < 16; ++s) {
    uint4 pk;
    pk.x = ((unsigned)f2bf(f0.y) << 16) | f2bf(f0.x);
    pk.y = ((unsigned)f2bf(f0.w) << 16) | f2bf(f0.z);
    pk.z = ((unsigned)f2bf(f1.y) << 16) | f2bf(f1.x);
    pk.w = ((unsigned)f2bf(f1.w) << 16) | f2bf(f1.z);
    if (s < 15) {       // prefetch next chunk; latency hides under barriers+mfma
      f0 = *(const float4*)(gp + (s + 1) * 32);
      f1 = *(const float4*)(gp + (s + 1) * 32 + 4);
    }
    *(uint4*)(xp + s * 32) = pk;
    *(uint4*)(As + lds_off) = pk;
    __syncthreads();
    short8 a = *(const short8*)(As + a_off);
    short8 b = *(const short8*)&uvs[lane & 15][s * 32 + (lane >> 4) * 8];
    acc = __builtin_amdgcn_mfma_f32_16x16x32_bf16(a, b, acc, 0, 0, 0);
    __syncthreads();
  }
  const int col = lane & 15;
  if (col < 6) {
    float* dst = (col < 3) ? left : right;
    const int t = (col < 3) ? col : col - 3;
    const int i = i0 + wid * 16 + ((lane >> 4) << 2);
    float* p = dst + ((size_t)t * 64 + n) * 512 + i;
    p[0] = acc.x; p[1] = acc.y; p[2] = acc.z; p[3] = acc.w;
  }
}

// ---------- 5. MFMA GEMM1: h2T[n][d][i] = (X[n] @ W2)^T ; XCD-swizzled, LDS-transposed store ----------
__global__ __launch_bounds__(256) void k_gemm1(const unsigned short* __restrict__ X,
                                               const unsigned short* __restrict__ WT,
                                               unsigned short* __restrict__ h2T) {
  __shared__ __attribute__((aligned(16))) char smem[34816];  // 16K staging | 128x136 bf16 Ct
  char* As = smem;
  char* Bs = smem + 8192;
  const int s = blockIdx.x;                 // same-n blocks -> same XCD (slot % 8)
  const int n  = ((s >> 7) << 3) | (s & 7);
  const int jj = (s >> 3) & 15;
  const int i0 = (jj >> 2) * 128;
  const int d0 = (jj & 3) * 128;
  const int tid = threadIdx.x;
  const int lane = tid & 63, w = tid >> 6;
  const int wm = w >> 1, wn = w & 1;
  const int srow = tid >> 2;
  const int kbp  = tid & 3;
  f32x4 acc[4][4];
#pragma unroll
  for (int a = 0; a < 4; ++a)
#pragma unroll
    for (int b = 0; b < 4; ++b) acc[a][b] = (f32x4){0.f, 0.f, 0.f, 0.f};

  const size_t xbase = (size_t)n * 262144;
  int ra[4], rb[4];
#pragma unroll
  for (int f = 0; f < 4; ++f) {
    int row = wm * 64 + f * 16 + (lane & 15);
    ra[f] = row * 64 + (((lane >> 4) ^ ((row >> 1) & 3)) << 4);
    int rowb = wn * 64 + f * 16 + (lane & 15);
    rb[f] = rowb * 64 + (((lane >> 4) ^ ((rowb >> 1) & 3)) << 4);
  }
  const int kl0 = (kbp ^ ((srow >> 1) & 3)) * 8;
  const int kl1 = (kbp ^ (((64 + srow) >> 1) & 3)) * 8;

  for (int kc = 0; kc < 512; kc += 32) {
    __syncthreads();
    GLOAD16(X + xbase + (size_t)(i0 + srow) * 512 + kc + kl0,       As + tid * 16);
    GLOAD16(X + xbase + (size_t)(i0 + 64 + srow) * 512 + kc + kl1,  As + 4096 + tid * 16);
    GLOAD16(WT + (size_t)(d0 + srow) * 512 + kc + kl0,              Bs + tid * 16);
    GLOAD16(WT + (size_t)(d0 + 64 + srow) * 512 + kc + kl1,         Bs + 4096 + tid * 16);
    __syncthreads();
    short8 a[4], b[4];
#pragma unroll
    for (int f = 0; f < 4; ++f) a[f] = *(const short8*)(As + ra[f]);
#pragma unroll
    for (int f = 0; f < 4; ++f) b[f] = *(const short8*)(Bs + rb[f]);
#pragma unroll
    for (int mf = 0; mf < 4; ++mf)
#pragma unroll
      for (int nf = 0; nf < 4; ++nf)
        acc[mf][nf] = __builtin_amdgcn_mfma_f32_16x16x32_bf16(a[mf], b[nf], acc[mf][nf], 0, 0, 0);
  }
  // epilogue: stage C into LDS [d][i] then write coalesced rows
  __syncthreads();
  unsigned short (*Ct)[136] = (unsigned short (*)[136])smem;
#pragma unroll
  for (int mf = 0; mf < 4; ++mf)
#pragma unroll
    for (int nf = 0; nf < 4; ++nf) {
      f32x4 vv = acc[mf][nf];
      int dl = wn * 64 + nf * 16 + (lane & 15);
      int il = wm * 64 + mf * 16 + ((lane >> 4) << 2);
      ushort4 pk;
      pk.x = f2bf(vv.x); pk.y = f2bf(vv.y); pk.z = f2bf(vv.z); pk.w = f2bf(vv.w);
      *(ushort4*)&Ct[dl][il] = pk;
    }
  __syncthreads();
  const size_t obase = xbase + (size_t)d0 * 512 + i0;
#pragma unroll
  for (int q = 0; q < 8; ++q) {
    int f = q * 2048 + tid * 8;
    int dl = f >> 7, il = f & 127;
    *(uint4*)&h2T[obase + (size_t)dl * 512 + il] = *(const uint4*)&Ct[dl][il];
  }
}

// ---------- 6. masked softmax -> coefs bf16 [n][i][j] ----------
__global__ __launch_bounds__(256) void k_softmax(const int* __restrict__ adj,
                                                 const float* __restrict__ left,
                                                 const float* __restrict__ right,
                                                 unsigned short* __restrict__ coefs) {
  const int n = blockIdx.y;
  const int wid = threadIdx.x >> 6, lane = threadIdx.x & 63;
  const int i = blockIdx.x * 4 + wid;
  __shared__ float rights[3][8][64];
  for (int idx = threadIdx.x; idx < 3 * 512; idx += 256) {
    int t = idx >> 9, j = idx & 511;
    rights[t][j & 7][j >> 3] = right[((size_t)t * 64 + n) * 512 + j];
  }
  __syncthreads();
  float l0 = left[((size_t)0 * 64 + n) * 512 + i];
  float l1 = left[((size_t)1 * 64 + n) * 512 + i];
  float l2 = left[((size_t)2 * 64 + n) * 512 + i];
  const int4* ap = (const int4*)(adj + ((size_t)n * 512 + i) * 512) + lane * 2;
  int4 a0 = ap[0], a1 = ap[1];
  int av[8] = {a0.x, a0.y, a0.z, a0.w, a1.x, a1.y, a1.z, a1.w};
  float s[8];
#pragma unroll
  for (int e = 0; e < 8; ++e) {
    int tv = av[e];
    if (tv == 0) s[e] = -9e15f;
    else {
      float lv = (tv == 1) ? l0 : (tv == 2) ? l1 : l2;
      float xv = lv + rights[tv - 1][e][lane];
      s[e] = (xv >= 0.f) ? xv : 0.2f * xv;
    }
  }
  float m = s[0];
#pragma unroll
  for (int e = 1; e < 8; ++e) m = fmaxf(m, s[e]);
  for (int off = 32; off > 0; off >>= 1) m = fmaxf(m, __shfl_xor(m, off));
  float p[8], sum = 0.f;
#pragma unroll
  for (int e = 0; e < 8; ++e) { p[e] = __expf(s[e] - m); sum += p[e]; }
  for (int off = 32; off > 0; off >>= 1) sum += __shfl_xor(sum, off);
  float inv = 1.f / sum;
  uint4 o;
  o.x = ((unsigned)f2bf(p[1] * inv) << 16) | f2bf(p[0] * inv);
  o.y = ((unsigned)f2bf(p[3] * inv) << 16) | f2bf(p[2] * inv);
  o.z = ((unsigned)f2bf(p[5] * inv) << 16) | f2bf(p[4] * inv);
  o.w = ((unsigned)f2bf(p[7] * inv) << 16) | f2bf(p[6] * inv);
  *(uint4*)(coefs + ((size_t)n * 512 + i) * 512 + lane * 8) = o;
}

// ---------- 7. transpose coefs[n][i][j] -> coefsT[n][j][i] (bf16) ----------
__global__ __launch_bounds__(256) void k_tr(const unsigned short* __restrict__ c,
                                            unsigned short* __restrict__ ct) {
  __shared__ __attribute__((aligned(16))) unsigned short t[64][72];
  const int n = blockIdx.z, i0 = blockIdx.y * 64, j0 = blockIdx.x * 64;
  const size_t base = (size_t)n * 262144;
  for (int idx = threadIdx.x; idx < 512; idx += 256) {
    int r = idx >> 3, cc = (idx & 7) * 8;
    *(uint4*)&t[r][cc] = *(const uint4*)&c[base + (size_t)(i0 + r) * 512 + j0 + cc];
  }
  __syncthreads();
  for (int idx = threadIdx.x; idx < 512; idx += 256) {
    int r = idx >> 3, cc = (idx & 7) * 8;   // r = j-local
    ushort4 o0, o1;
    o0.x = t[cc + 0][r]; o0.y = t[cc + 1][r]; o0.z = t[cc + 2][r]; o0.w = t[cc + 3][r];
    o1.x = t[cc + 4][r]; o1.y = t[cc + 5][r]; o1.z = t[cc + 6][r]; o1.w = t[cc + 7][r];
    *(ushort4*)&ct[base + (size_t)(j0 + r) * 512 + i0 + cc]     = o0;
    *(ushort4*)&ct[base + (size_t)(j0 + r) * 512 + i0 + cc + 4] = o1;
  }
}

// ---------- 8. MFMA GEMM2: out[n][j][d] = coefsT[n] @ h2T[n]^T ; XCD-swizzled ----------
__global__ __launch_bounds__(256) void k_gemm2(const unsigned short* __restrict__ CT,
                                               const unsigned short* __restrict__ H2T,
                                               float* __restrict__ out) {
  const int s = blockIdx.x;
  const int n  = ((s >> 7) << 3) | (s & 7);
  const int jj = (s >> 3) & 15;
  const int j0 = (jj >> 2) * 128;
  const int d0 = (jj & 3) * 128;
  const int tid = threadIdx.x;
  const int lane = tid & 63, w = tid >> 6;
  const int wm = w >> 1, wn = w & 1;
  __shared__ __attribute__((aligned(16))) char As[8192];
  __shared__ __attribute__((aligned(16))) char Bs[8192];
  const int srow = tid >> 2;
  const int kbp  = tid & 3;
  f32x4 acc[4][4];
#pragma unroll
  for (int a = 0; a < 4; ++a)
#pragma unroll
    for (int b = 0; b < 4; ++b) acc[a][b] = (f32x4){0.f, 0.f, 0.f, 0.f};

  const size_t base = (size_t)n * 262144;
  int ra[4], rb[4];
#pragma unroll
  for (int f = 0; f < 4; ++f) {
    int row = wm * 64 + f * 16 + (lane & 15);
    ra[f] = row * 64 + (((lane >> 4) ^ ((row >> 1) & 3)) << 4);
    int rowb = wn * 64 + f * 16 + (lane & 15);
    rb[f] = rowb * 64 + (((lane >> 4) ^ ((rowb >> 1) & 3)) << 4);
  }
  const int kl0 = (kbp ^ ((srow >> 1) & 3)) * 8;
  const int kl1 = (kbp ^ (((64 + srow) >> 1) & 3)) * 8;

  for (int kc = 0; kc < 512; kc += 32) {
    __syncthreads();
    GLOAD16(CT + base + (size_t)(j0 + srow) * 512 + kc + kl0,       As + tid * 16);
    GLOAD16(CT + base + (size_t)(j0 + 64 + srow) * 512 + kc + kl1,  As + 4096 + tid * 16);
    GLOAD16(H2T + base + (size_t)(d0 + srow) * 512 + kc + kl0,      Bs + tid * 16);
    GLOAD16(H2T + base + (size_t)(d0 + 64 + srow) * 512 + kc + kl1, Bs + 4096 + tid * 16);
    __syncthreads();
    short8 a[4], b[4];
#pragma unroll
    for (int f = 0; f < 4; ++f) a[f] = *(const short8*)(As + ra[f]);
#pragma unroll
    for (int f = 0; f < 4; ++f) b[f] = *(const short8*)(Bs + rb[f]);
#pragma unroll
    for (int mf = 0; mf < 4; ++mf)
#pragma unroll
      for (int nf = 0; nf < 4; ++nf)
        acc[mf][nf] = __builtin_amdgcn_mfma_f32_16x16x32_bf16(a[mf], b[nf], acc[mf][nf], 0, 0, 0);
  }
  const int jb = j0 + wm * 64 + (lane >> 4) * 4;
  const int db = d0 + wn * 64 + (lane & 15);
#pragma unroll
  for (int mf = 0; mf < 4; ++mf)
#pragma unroll
    for (int nf = 0; nf < 4; ++nf) {
      f32x4 vv = acc[mf][nf];
      float* op = out + base + (size_t)(jb + mf * 16) * 512 + db + nf * 16;
      op[0]    = vv.x;
      op[512]  = vv.y;
      op[1024] = vv.z;
      op[1536] = vv.w;
    }
}

extern "C" void kernel_launch(void* const* d_in, const int* in_sizes, int n_in,
                              void* d_out, int out_size, void* d_ws, size_t ws_size,
                              hipStream_t stream) {
  const float* input  = (const float*)d_in[0];
  const int*   adj    = (const int*)d_in[1];
  const float* query  = (const float*)d_in[3];
  const float* W_type = (const float*)d_in[4];
  const float* a_type = (const float*)d_in[5];
  const float* W1     = (const float*)d_in[6];
  const float* W2     = (const float*)d_in[7];
  float* out = (float*)d_out;

  char* ws = (char*)d_ws;
  float* galT  = (float*)(ws);                              //  393,216 B
  float* garT  = (float*)(ws + 393216);                     //  393,216 B
  unsigned short* uvbf = (unsigned short*)(ws + 786432);    //  393,216 B
  float* left  = (float*)(ws + 1179648);                    //  393,216 B
  float* right = (float*)(ws + 1572864);                    //  393,216 B
  unsigned short* Xbf = (unsigned short*)(ws + 2359296);    // 33,554,432 B (reused as coefsT)
  unsigned short* h2T = (unsigned short*)(ws + 35913728);   // 33,554,432 B
  // partials alias h2T's region: all dead before k_gemm1 writes h2T
  float* rpart = (float*)(ws + 35913728);                   //  3,145,728 B
  float* gpart = (float*)(ws + 39059456);                   //  6,291,456 B
  float* upart = (float*)(ws + 45350912);                   //  3,145,728 B
  float* vpart = (float*)(ws + 48496640);                   //  3,145,728 B
  unsigned short* WT  = (unsigned short*)(ws + 69468160);   //    524,288 B
  // total ws use: 69,992,448 B
  unsigned short* coefs  = (unsigned short*)d_out;  // parked in d_out, dead before GEMM2 writes
  unsigned short* coefsT = Xbf;                     // Xbf dead after k_gemm1

  k_wt      <<<dim3(8, 8),      256, 0, stream>>>(W_type + (size_t)2 * 262144, WT);
  k_gate1   <<<dim3(16, 4, 3),  256, 0, stream>>>(query, W1, rpart);
  k_gate2   <<<dim3(16, 8, 3),  256, 0, stream>>>(rpart, W2, gpart);
  k_gate_fin<<<dim3(256, 3),    256, 0, stream>>>(gpart, a_type, galT, garT);
  k_uvp     <<<dim3(8, 8, 3),   256, 0, stream>>>(W_type, galT, garT, upart, vpart);
  k_uvsum   <<<dim3(64),        256, 0, stream>>>(upart, vpart, uvbf);
  k_lrm     <<<dim3(8, 64),     256, 0, stream>>>(input, uvbf, left, right, Xbf);
  k_gemm1   <<<dim3(1024),      256, 0, stream>>>(Xbf, WT, h2T);
  k_softmax <<<dim3(128, 64),   256, 0, stream>>>(adj, left, right, coefs);
  k_tr      <<<dim3(8, 8, 64),  256, 0, stream>>>(coefs, coefsT);
  k_gemm2   <<<dim3(1024),      256, 0, stream>>>(coefsT, h2T, out);
}

// Round 6
// 195.929 us; speedup vs baseline: 3.1191x; 1.0101x over previous
//
#include <hip/hip_runtime.h>
#include <cstdint>

typedef __attribute__((ext_vector_type(8))) short short8;
typedef __attribute__((ext_vector_type(4))) float f32x4;

// ---------- helpers ----------
__device__ __forceinline__ unsigned short f2bf(float x) {
  unsigned int u = __float_as_uint(x);
  u += 0x7FFFu + ((u >> 16) & 1u);   // round-to-nearest-even
  return (unsigned short)(u >> 16);
}

#define GLOAD16(gsrc, ldst)                                                        \
  __builtin_amdgcn_global_load_lds(                                                \
      (const __attribute__((address_space(1))) void*)(gsrc),                       \
      (__attribute__((address_space(3))) void*)(ldst), 16, 0, 0)

// ---------- 0b. WT[d][k] = bf16(W2[k][d]) ----------
__global__ __launch_bounds__(256) void k_wt(const float* __restrict__ W,
                                            unsigned short* __restrict__ WT) {
  __shared__ float t[64][68];
  const int k0 = blockIdx.y * 64, d0 = blockIdx.x * 64;
  for (int idx = threadIdx.x; idx < 4096; idx += 256) {
    int r = idx >> 6, c = idx & 63;
    t[r][c] = W[(size_t)(k0 + r) * 512 + d0 + c];
  }
  __syncthreads();
  for (int idx = threadIdx.x; idx < 4096; idx += 256) {
    int r = idx >> 6, c = idx & 63;     // r = d-local, c = k-local
    WT[(size_t)(d0 + r) * 512 + k0 + c] = f2bf(t[c][r]);
  }
}

// ---------- gate 1: rpart[t][kc][col][n] = partial (q @ W1[t]) ----------
__global__ __launch_bounds__(256) void k_gate1(const float* __restrict__ q,
                                               const float* __restrict__ W1,
                                               float* __restrict__ rpart) {
  const int c0 = blockIdx.x * 64;
  const int k0 = blockIdx.y * 128;
  const int t  = blockIdx.z;
  const int tid = threadIdx.x;
  const int lane = tid & 63;           // row n
  const int wcs = __builtin_amdgcn_readfirstlane(tid >> 6);
  __shared__ float qs[64][133];
  for (int idx = tid; idx < 2048; idx += 256) {
    int r = idx >> 5, c4 = (idx & 31) * 4;
    float4 f = *(const float4*)&q[(size_t)r * 512 + k0 + c4];
    qs[r][c4 + 0] = f.x; qs[r][c4 + 1] = f.y;
    qs[r][c4 + 2] = f.z; qs[r][c4 + 3] = f.w;
  }
  __syncthreads();
  const float* Wp = W1 + ((size_t)t * 512 + k0) * 1024 + c0 + wcs * 16;
  float acc[16] = {};
  for (int k = 0; k < 128; ++k) {
    float qr = qs[lane][k];
    const float* wr = Wp + (size_t)k * 1024;
    float4 w0 = *(const float4*)(wr);
    float4 w1 = *(const float4*)(wr + 4);
    float4 w2 = *(const float4*)(wr + 8);
    float4 w3 = *(const float4*)(wr + 12);
    acc[0]  = fmaf(qr, w0.x, acc[0]);  acc[1]  = fmaf(qr, w0.y, acc[1]);
    acc[2]  = fmaf(qr, w0.z, acc[2]);  acc[3]  = fmaf(qr, w0.w, acc[3]);
    acc[4]  = fmaf(qr, w1.x, acc[4]);  acc[5]  = fmaf(qr, w1.y, acc[5]);
    acc[6]  = fmaf(qr, w1.z, acc[6]);  acc[7]  = fmaf(qr, w1.w, acc[7]);
    acc[8]  = fmaf(qr, w2.x, acc[8]);  acc[9]  = fmaf(qr, w2.y, acc[9]);
    acc[10] = fmaf(qr, w2.z, acc[10]); acc[11] = fmaf(qr, w2.w, acc[11]);
    acc[12] = fmaf(qr, w3.x, acc[12]); acc[13] = fmaf(qr, w3.y, acc[13]);
    acc[14] = fmaf(qr, w3.z, acc[14]); acc[15] = fmaf(qr, w3.w, acc[15]);
  }
  float* rp = rpart + ((size_t)(t * 4 + blockIdx.y) * 1024 + c0 + wcs * 16) * 64 + lane;
#pragma unroll
  for (int cc = 0; cc < 16; ++cc) rp[(size_t)cc * 64] = acc[cc];
}

// ---------- gate 2: gpart[t][kc][col][n] = partial (relu(r) @ W2[t]) ----------
__global__ __launch_bounds__(256) void k_gate2(const float* __restrict__ rpart,
                                               const float* __restrict__ W2,
                                               float* __restrict__ gpart) {
  const int c0 = blockIdx.x * 64;
  const int k0 = blockIdx.y * 128;
  const int t  = blockIdx.z;
  const int tid = threadIdx.x;
  const int lane = tid & 63;
  const int wcs = __builtin_amdgcn_readfirstlane(tid >> 6);
  __shared__ float qs[64][133];
  for (int idx = tid; idx < 2048; idx += 256) {
    int kl = idx >> 4, n4 = (idx & 15) * 4;
    const float* rp = rpart + ((size_t)t * 4 * 1024 + k0 + kl) * 64 + n4;
    float4 a = *(const float4*)(rp);
    float4 b = *(const float4*)(rp + 65536);
    float4 c = *(const float4*)(rp + 131072);
    float4 d = *(const float4*)(rp + 196608);
    qs[n4 + 0][kl] = fmaxf(a.x + b.x + c.x + d.x, 0.f);
    qs[n4 + 1][kl] = fmaxf(a.y + b.y + c.y + d.y, 0.f);
    qs[n4 + 2][kl] = fmaxf(a.z + b.z + c.z + d.z, 0.f);
    qs[n4 + 3][kl] = fmaxf(a.w + b.w + c.w + d.w, 0.f);
  }
  __syncthreads();
  const float* Wp = W2 + ((size_t)t << 20) + (size_t)k0 * 1024 + c0 + wcs * 16;
  float acc[16] = {};
  for (int k = 0; k < 128; ++k) {
    float qr = qs[lane][k];
    const float* wr = Wp + (size_t)k * 1024;
    float4 w0 = *(const float4*)(wr);
    float4 w1 = *(const float4*)(wr + 4);
    float4 w2 = *(const float4*)(wr + 8);
    float4 w3 = *(const float4*)(wr + 12);
    acc[0]  = fmaf(qr, w0.x, acc[0]);  acc[1]  = fmaf(qr, w0.y, acc[1]);
    acc[2]  = fmaf(qr, w0.z, acc[2]);  acc[3]  = fmaf(qr, w0.w, acc[3]);
    acc[4]  = fmaf(qr, w1.x, acc[4]);  acc[5]  = fmaf(qr, w1.y, acc[5]);
    acc[6]  = fmaf(qr, w1.z, acc[6]);  acc[7]  = fmaf(qr, w1.w, acc[7]);
    acc[8]  = fmaf(qr, w2.x, acc[8]);  acc[9]  = fmaf(qr, w2.y, acc[9]);
    acc[10] = fmaf(qr, w2.z, acc[10]); acc[11] = fmaf(qr, w2.w, acc[11]);
    acc[12] = fmaf(qr, w3.x, acc[12]); acc[13] = fmaf(qr, w3.y, acc[13]);
    acc[14] = fmaf(qr, w3.z, acc[14]); acc[15] = fmaf(qr, w3.w, acc[15]);
  }
  float* gp = gpart + ((size_t)(t * 8 + blockIdx.y) * 1024 + c0 + wcs * 16) * 64 + lane;
#pragma unroll
  for (int cc = 0; cc < 16; ++cc) gp[(size_t)cc * 64] = acc[cc];
}

// ---------- gate fin: sigmoid(sum) * a -> galT/garT ----------
__global__ __launch_bounds__(256) void k_gate_fin(const float* __restrict__ gpart,
                                                  const float* __restrict__ a_type,
                                                  float* __restrict__ galT,
                                                  float* __restrict__ garT) {
  const int t = blockIdx.y;
  const int n = threadIdx.x & 63;
  const int mg = blockIdx.x * 4 + (threadIdx.x >> 6);
  float s = 0.f;
#pragma unroll
  for (int kc = 0; kc < 8; ++kc)
    s += gpart[((size_t)(t * 8 + kc) * 1024 + mg) * 64 + n];
  float g = 1.f / (1.f + __expf(-s));
  float ga = g * a_type[t * 1024 + mg];
  if (mg < 512) galT[((size_t)t * 512 + mg) * 64 + n] = ga;
  else          garT[((size_t)t * 512 + (mg - 512)) * 64 + n] = ga;
}

// ---------- 3. u,v split-d partials ----------
__global__ __launch_bounds__(256) void k_uvp(const float* __restrict__ W,
                                             const float* __restrict__ galT,
                                             const float* __restrict__ garT,
                                             float* __restrict__ upart,
                                             float* __restrict__ vpart) {
  const int k0 = blockIdx.x * 64;
  const int d0 = blockIdx.y * 64;
  const int t  = blockIdx.z;
  const int tid = threadIdx.x;
  const int lane = tid & 63;           // lane = n
  const int wk = (tid >> 6) * 16;      // wave's k-subtile
  __shared__ float gal_s[64][64];      // [d][n]
  __shared__ float gar_s[64][64];
  __shared__ float W_s[64][64];        // [k][d]
  for (int idx = tid; idx < 1024; idx += 256) {
    int d = idx >> 4, n4 = (idx & 15) * 4;
    *(float4*)&gal_s[d][n4] = *(const float4*)&galT[((size_t)t * 512 + d0 + d) * 64 + n4];
    *(float4*)&gar_s[d][n4] = *(const float4*)&garT[((size_t)t * 512 + d0 + d) * 64 + n4];
    int k = idx >> 4, d4 = (idx & 15) * 4;
    *(float4*)&W_s[k][d4] = *(const float4*)&W[((size_t)t * 512 + k0 + k) * 512 + d0 + d4];
  }
  __syncthreads();
  float au[16] = {}, av[16] = {};
  for (int dq = 0; dq < 64; dq += 4) {
    float g1[4], g2[4];
#pragma unroll
    for (int e = 0; e < 4; ++e) { g1[e] = gal_s[dq + e][lane]; g2[e] = gar_s[dq + e][lane]; }
#pragma unroll
    for (int kk = 0; kk < 16; ++kk) {
      float4 wv = *(const float4*)&W_s[wk + kk][dq];
      au[kk] = fmaf(wv.x, g1[0], fmaf(wv.y, g1[1], fmaf(wv.z, g1[2], fmaf(wv.w, g1[3], au[kk]))));
      av[kk] = fmaf(wv.x, g2[0], fmaf(wv.y, g2[1], fmaf(wv.z, g2[2], fmaf(wv.w, g2[3], av[kk]))));
    }
  }
  const size_t ob = ((size_t)((t * 8 + blockIdx.y) * 64 + lane)) * 512 + k0 + wk;
#pragma unroll
  for (int q = 0; q < 4; ++q) {
    *(float4*)&upart[ob + q * 4] = make_float4(au[q*4], au[q*4+1], au[q*4+2], au[q*4+3]);
    *(float4*)&vpart[ob + q * 4] = make_float4(av[q*4], av[q*4+1], av[q*4+2], av[q*4+3]);
  }
}

// ---------- 3b. sum uv partials -> uvbf[n][6][512] bf16 ----------
__global__ __launch_bounds__(256) void k_uvsum(const float* __restrict__ upart,
                                               const float* __restrict__ vpart,
                                               unsigned short* __restrict__ uvbf) {
  const int n = blockIdx.x;
  for (int idx = threadIdx.x; idx < 768; idx += 256) {
    int col = idx >> 7;              // 0..5
    int k4 = (idx & 127) * 4;
    const float* base = (col < 3)
        ? upart + ((size_t)(col * 8) * 64 + n) * 512 + k4
        : vpart + ((size_t)((col - 3) * 8) * 64 + n) * 512 + k4;
    float4 sv = {0.f, 0.f, 0.f, 0.f};
#pragma unroll
    for (int dc = 0; dc < 8; ++dc) {
      float4 t = *(const float4*)(base + (size_t)dc * 32768);
      sv.x += t.x; sv.y += t.y; sv.z += t.z; sv.w += t.w;
    }
    ushort4 o;
    o.x = f2bf(sv.x); o.y = f2bf(sv.y); o.z = f2bf(sv.z); o.w = f2bf(sv.w);
    *(ushort4*)&uvbf[((size_t)n * 6 + col) * 512 + k4] = o;
  }
}

// ---------- 4. k_lrm: single pass over X: f32->bf16 conversion + left/right via MFMA ----------
__global__ __launch_bounds__(256) void k_lrm(const float* __restrict__ x,
                                             const unsigned short* __restrict__ uvbf,
                                             float* __restrict__ left,
                                             float* __restrict__ right,
                                             unsigned short* __restrict__ Xbf) {
  const int n  = blockIdx.y;
  const int i0 = blockIdx.x * 64;
  const int tid = threadIdx.x;
  const int lane = tid & 63, wid = tid >> 6;
  __shared__ unsigned short uvs[16][520];
  __shared__ __attribute__((aligned(16))) char As[4096];

  for (int idx = tid; idx < 16 * 64; idx += 256) {
    int col = idx >> 6, k8 = (idx & 63) * 8;
    ushort4 z0 = {0, 0, 0, 0}, z1 = {0, 0, 0, 0};
    if (col < 6) {
      const unsigned short* p = uvbf + ((size_t)n * 6 + col) * 512 + k8;
      z0 = *(const ushort4*)p;
      z1 = *(const ushort4*)(p + 4);
    }
    *(ushort4*)&uvs[col][k8]     = z0;
    *(ushort4*)&uvs[col][k8 + 4] = z1;
  }
  const int row = tid >> 2, sub = tid & 3;
  const float* gp = x + ((size_t)n * 512 + i0 + row) * 512 + sub * 8;
  unsigned short* xp = Xbf + ((size_t)n * 512 + i0 + row) * 512 + sub * 8;
  const int lds_off = row * 64 + ((sub ^ (row & 3)) << 4);
  const int arow = wid * 16 + (lane & 15);
  const int a_off = arow * 64 + (((lane >> 4) ^ (arow & 3)) << 4);
  f32x4 acc = {0.f, 0.f, 0.f, 0.f};
  float4 f0 = *(const float4*)(gp);
  float4 f1 = *(const float4*)(gp + 4);
  __syncthreads();
  for (int s = 0; s < 16; ++s) {
    uint4 pk;
    pk.x = ((unsigned)f2bf(f0.y) << 16) | f2bf(f0.x);
    pk.y = ((unsigned)f2bf(f0.w) << 16) | f2bf(f0.z);
    pk.z = ((unsigned)f2bf(f1.y) << 16) | f2bf(f1.x);
    pk.w = ((unsigned)f2bf(f1.w) << 16) | f2bf(f1.z);
    if (s < 15) {
      f0 = *(const float4*)(gp + (s + 1) * 32);
      f1 = *(const float4*)(gp + (s + 1) * 32 + 4);
    }
    *(uint4*)(xp + s * 32) = pk;
    *(uint4*)(As + lds_off) = pk;
    __syncthreads();
    short8 a = *(const short8*)(As + a_off);
    short8 b = *(const short8*)&uvs[lane & 15][s * 32 + (lane >> 4) * 8];
    acc = __builtin_amdgcn_mfma_f32_16x16x32_bf16(a, b, acc, 0, 0, 0);
    __syncthreads();
  }
  const int col = lane & 15;
  if (col < 6) {
    float* dst = (col < 3) ? left : right;
    const int t = (col < 3) ? col : col - 3;
    const int i = i0 + wid * 16 + ((lane >> 4) << 2);
    float* p = dst + ((size_t)t * 64 + n) * 512 + i;
    p[0] = acc.x; p[1] = acc.y; p[2] = acc.z; p[3] = acc.w;
  }
}

// ---------- 5. MFMA GEMM1: h2T[n][d][i] = (X[n] @ W2)^T ; XCD-swizzled, LDS-transposed store ----------
__global__ __launch_bounds__(256) void k_gemm1(const unsigned short* __restrict__ X,
                                               const unsigned short* __restrict__ WT,
                                               unsigned short* __restrict__ h2T) {
  __shared__ __attribute__((aligned(16))) char smem[34816];
  char* As = smem;
  char* Bs = smem + 8192;
  const int s = blockIdx.x;
  const int n  = ((s >> 7) << 3) | (s & 7);
  const int jj = (s >> 3) & 15;
  const int i0 = (jj >> 2) * 128;
  const int d0 = (jj & 3) * 128;
  const int tid = threadIdx.x;
  const int lane = tid & 63, w = tid >> 6;
  const int wm = w >> 1, wn = w & 1;
  const int srow = tid >> 2;
  const int kbp  = tid & 3;
  f32x4 acc[4][4];
#pragma unroll
  for (int a = 0; a < 4; ++a)
#pragma unroll
    for (int b = 0; b < 4; ++b) acc[a][b] = (f32x4){0.f, 0.f, 0.f, 0.f};

  const size_t xbase = (size_t)n * 262144;
  int ra[4], rb[4];
#pragma unroll
  for (int f = 0; f < 4; ++f) {
    int row = wm * 64 + f * 16 + (lane & 15);
    ra[f] = row * 64 + (((lane >> 4) ^ ((row >> 1) & 3)) << 4);
    int rowb = wn * 64 + f * 16 + (lane & 15);
    rb[f] = rowb * 64 + (((lane >> 4) ^ ((rowb >> 1) & 3)) << 4);
  }
  const int kl0 = (kbp ^ ((srow >> 1) & 3)) * 8;
  const int kl1 = (kbp ^ (((64 + srow) >> 1) & 3)) * 8;

  for (int kc = 0; kc < 512; kc += 32) {
    __syncthreads();
    GLOAD16(X + xbase + (size_t)(i0 + srow) * 512 + kc + kl0,       As + tid * 16);
    GLOAD16(X + xbase + (size_t)(i0 + 64 + srow) * 512 + kc + kl1,  As + 4096 + tid * 16);
    GLOAD16(WT + (size_t)(d0 + srow) * 512 + kc + kl0,              Bs + tid * 16);
    GLOAD16(WT + (size_t)(d0 + 64 + srow) * 512 + kc + kl1,         Bs + 4096 + tid * 16);
    __syncthreads();
    short8 a[4], b[4];
#pragma unroll
    for (int f = 0; f < 4; ++f) a[f] = *(const short8*)(As + ra[f]);
#pragma unroll
    for (int f = 0; f < 4; ++f) b[f] = *(const short8*)(Bs + rb[f]);
#pragma unroll
    for (int mf = 0; mf < 4; ++mf)
#pragma unroll
      for (int nf = 0; nf < 4; ++nf)
        acc[mf][nf] = __builtin_amdgcn_mfma_f32_16x16x32_bf16(a[mf], b[nf], acc[mf][nf], 0, 0, 0);
  }
  __syncthreads();
  unsigned short (*Ct)[136] = (unsigned short (*)[136])smem;
#pragma unroll
  for (int mf = 0; mf < 4; ++mf)
#pragma unroll
    for (int nf = 0; nf < 4; ++nf) {
      f32x4 vv = acc[mf][nf];
      int dl = wn * 64 + nf * 16 + (lane & 15);
      int il = wm * 64 + mf * 16 + ((lane >> 4) << 2);
      ushort4 pk;
      pk.x = f2bf(vv.x); pk.y = f2bf(vv.y); pk.z = f2bf(vv.z); pk.w = f2bf(vv.w);
      *(ushort4*)&Ct[dl][il] = pk;
    }
  __syncthreads();
  const size_t obase = xbase + (size_t)d0 * 512 + i0;
#pragma unroll
  for (int q = 0; q < 8; ++q) {
    int f = q * 2048 + tid * 8;
    int dl = f >> 7, il = f & 127;
    *(uint4*)&h2T[obase + (size_t)dl * 512 + il] = *(const uint4*)&Ct[dl][il];
  }
}

// ---------- 6. fused masked softmax + transpose -> coefsT[n][j][i] bf16 ----------
// grid (16 i-tiles of 32, 64 n), 256 thr / 4 waves; wave handles 8 rows.
// j-mapping: j = e*64 + lane  (coalesced adj loads; conflict-free transposed LDS store)
__global__ __launch_bounds__(256) void k_smt(const int* __restrict__ adj,
                                             const float* __restrict__ left,
                                             const float* __restrict__ right,
                                             unsigned short* __restrict__ ct) {
  const int n  = blockIdx.y;
  const int i0 = blockIdx.x * 32;
  const int tid = threadIdx.x;
  const int lane = tid & 63, wid = tid >> 6;
  __shared__ float rs[3][512];
  __shared__ float ls[3][32];
  __shared__ unsigned short tile[512][34];   // [j][i-local], 17-word pitch -> conflict-free
  for (int idx = tid; idx < 1536; idx += 256) {
    int t = idx >> 9, j = idx & 511;
    rs[t][j] = right[((size_t)t * 64 + n) * 512 + j];
  }
  if (tid < 96) {
    int t = tid >> 5, il = tid & 31;
    ls[t][il] = left[((size_t)t * 64 + n) * 512 + i0 + il];
  }
  __syncthreads();
  const int* adjb = adj + ((size_t)n * 512 + i0) * 512;
  int tvA[8];
#pragma unroll
  for (int e = 0; e < 8; ++e) tvA[e] = adjb[(size_t)(wid * 8) * 512 + e * 64 + lane];
  for (int r = 0; r < 8; ++r) {
    const int il = wid * 8 + r;
    int tv[8];
#pragma unroll
    for (int e = 0; e < 8; ++e) tv[e] = tvA[e];
    if (r < 7) {
      const int* nxt = adjb + (size_t)(il + 1) * 512;
#pragma unroll
      for (int e = 0; e < 8; ++e) tvA[e] = nxt[e * 64 + lane];
    }
    const float l0 = ls[0][il], l1 = ls[1][il], l2 = ls[2][il];
    float s[8];
#pragma unroll
    for (int e = 0; e < 8; ++e) {
      int t = tv[e];
      if (t == 0) s[e] = -9e15f;
      else {
        float lv = (t == 1) ? l0 : (t == 2) ? l1 : l2;
        float xv = lv + rs[t - 1][e * 64 + lane];
        s[e] = (xv >= 0.f) ? xv : 0.2f * xv;
      }
    }
    float m = fmaxf(fmaxf(fmaxf(s[0], s[1]), fmaxf(s[2], s[3])),
                    fmaxf(fmaxf(s[4], s[5]), fmaxf(s[6], s[7])));
    for (int off = 32; off > 0; off >>= 1) m = fmaxf(m, __shfl_xor(m, off));
    float p[8], sum = 0.f;
#pragma unroll
    for (int e = 0; e < 8; ++e) { p[e] = __expf(s[e] - m); sum += p[e]; }
    for (int off = 32; off > 0; off >>= 1) sum += __shfl_xor(sum, off);
    const float inv = 1.f / sum;
#pragma unroll
    for (int e = 0; e < 8; ++e) tile[e * 64 + lane][il] = f2bf(p[e] * inv);
  }
  __syncthreads();
  // writeout: 8 passes; thread -> (j = pass*64 + tid>>2, i8 = (tid&3)*8); 16B per thread
  unsigned short* ob = ct + (size_t)n * 262144 + i0;
#pragma unroll
  for (int pass = 0; pass < 8; ++pass) {
    int j = pass * 64 + (tid >> 2);
    int i8 = (tid & 3) * 8;
    const unsigned short* tp = &tile[j][i8];
    uint4 o;
    o.x = *(const unsigned int*)(tp);
    o.y = *(const unsigned int*)(tp + 2);
    o.z = *(const unsigned int*)(tp + 4);
    o.w = *(const unsigned int*)(tp + 6);
    *(uint4*)&ob[(size_t)j * 512 + i8] = o;
  }
}

// ---------- 8. MFMA GEMM2: out[n][j][d] = coefsT[n] @ h2T[n]^T ; XCD-swizzled ----------
__global__ __launch_bounds__(256) void k_gemm2(const unsigned short* __restrict__ CT,
                                               const unsigned short* __restrict__ H2T,
                                               float* __restrict__ out) {
  const int s = blockIdx.x;
  const int n  = ((s >> 7) << 3) | (s & 7);
  const int jj = (s >> 3) & 15;
  const int j0 = (jj >> 2) * 128;
  const int d0 = (jj & 3) * 128;
  const int tid = threadIdx.x;
  const int lane = tid & 63, w = tid >> 6;
  const int wm = w >> 1, wn = w & 1;
  __shared__ __attribute__((aligned(16))) char As[8192];
  __shared__ __attribute__((aligned(16))) char Bs[8192];
  const int srow = tid >> 2;
  const int kbp  = tid & 3;
  f32x4 acc[4][4];
#pragma unroll
  for (int a = 0; a < 4; ++a)
#pragma unroll
    for (int b = 0; b < 4; ++b) acc[a][b] = (f32x4){0.f, 0.f, 0.f, 0.f};

  const size_t base = (size_t)n * 262144;
  int ra[4], rb[4];
#pragma unroll
  for (int f = 0; f < 4; ++f) {
    int row = wm * 64 + f * 16 + (lane & 15);
    ra[f] = row * 64 + (((lane >> 4) ^ ((row >> 1) & 3)) << 4);
    int rowb = wn * 64 + f * 16 + (lane & 15);
    rb[f] = rowb * 64 + (((lane >> 4) ^ ((rowb >> 1) & 3)) << 4);
  }
  const int kl0 = (kbp ^ ((srow >> 1) & 3)) * 8;
  const int kl1 = (kbp ^ (((64 + srow) >> 1) & 3)) * 8;

  for (int kc = 0; kc < 512; kc += 32) {
    __syncthreads();
    GLOAD16(CT + base + (size_t)(j0 + srow) * 512 + kc + kl0,       As + tid * 16);
    GLOAD16(CT + base + (size_t)(j0 + 64 + srow) * 512 + kc + kl1,  As + 4096 + tid * 16);
    GLOAD16(H2T + base + (size_t)(d0 + srow) * 512 + kc + kl0,      Bs + tid * 16);
    GLOAD16(H2T + base + (size_t)(d0 + 64 + srow) * 512 + kc + kl1, Bs + 4096 + tid * 16);
    __syncthreads();
    short8 a[4], b[4];
#pragma unroll
    for (int f = 0; f < 4; ++f) a[f] = *(const short8*)(As + ra[f]);
#pragma unroll
    for (int f = 0; f < 4; ++f) b[f] = *(const short8*)(Bs + rb[f]);
#pragma unroll
    for (int mf = 0; mf < 4; ++mf)
#pragma unroll
      for (int nf = 0; nf < 4; ++nf)
        acc[mf][nf] = __builtin_amdgcn_mfma_f32_16x16x32_bf16(a[mf], b[nf], acc[mf][nf], 0, 0, 0);
  }
  const int jb = j0 + wm * 64 + (lane >> 4) * 4;
  const int db = d0 + wn * 64 + (lane & 15);
#pragma unroll
  for (int mf = 0; mf < 4; ++mf)
#pragma unroll
    for (int nf = 0; nf < 4; ++nf) {
      f32x4 vv = acc[mf][nf];
      float* op = out + base + (size_t)(jb + mf * 16) * 512 + db + nf * 16;
      op[0]    = vv.x;
      op[512]  = vv.y;
      op[1024] = vv.z;
      op[1536] = vv.w;
    }
}

extern "C" void kernel_launch(void* const* d_in, const int* in_sizes, int n_in,
                              void* d_out, int out_size, void* d_ws, size_t ws_size,
                              hipStream_t stream) {
  const float* input  = (const float*)d_in[0];
  const int*   adj    = (const int*)d_in[1];
  const float* query  = (const float*)d_in[3];
  const float* W_type = (const float*)d_in[4];
  const float* a_type = (const float*)d_in[5];
  const float* W1     = (const float*)d_in[6];
  const float* W2     = (const float*)d_in[7];
  float* out = (float*)d_out;

  char* ws = (char*)d_ws;
  float* galT  = (float*)(ws);                              //  393,216 B
  float* garT  = (float*)(ws + 393216);                     //  393,216 B
  unsigned short* uvbf = (unsigned short*)(ws + 786432);    //  393,216 B
  float* left  = (float*)(ws + 1179648);                    //  393,216 B
  float* right = (float*)(ws + 1572864);                    //  393,216 B
  unsigned short* Xbf = (unsigned short*)(ws + 2359296);    // 33,554,432 B (reused as coefsT)
  unsigned short* h2T = (unsigned short*)(ws + 35913728);   // 33,554,432 B
  // partials alias h2T's region: all dead before k_gemm1 writes h2T
  float* rpart = (float*)(ws + 35913728);                   //  3,145,728 B
  float* gpart = (float*)(ws + 39059456);                   //  6,291,456 B
  float* upart = (float*)(ws + 45350912);                   //  3,145,728 B
  float* vpart = (float*)(ws + 48496640);                   //  3,145,728 B
  unsigned short* WT  = (unsigned short*)(ws + 69468160);   //    524,288 B
  // total ws use: 69,992,448 B
  unsigned short* coefsT = Xbf;   // Xbf dead after k_gemm1; k_smt writes it, k_gemm2 reads it

  k_wt      <<<dim3(8, 8),      256, 0, stream>>>(W_type + (size_t)2 * 262144, WT);
  k_gate1   <<<dim3(16, 4, 3),  256, 0, stream>>>(query, W1, rpart);
  k_gate2   <<<dim3(16, 8, 3),  256, 0, stream>>>(rpart, W2, gpart);
  k_gate_fin<<<dim3(256, 3),    256, 0, stream>>>(gpart, a_type, galT, garT);
  k_uvp     <<<dim3(8, 8, 3),   256, 0, stream>>>(W_type, galT, garT, upart, vpart);
  k_uvsum   <<<dim3(64),        256, 0, stream>>>(upart, vpart, uvbf);
  k_lrm     <<<dim3(8, 64),     256, 0, stream>>>(input, uvbf, left, right, Xbf);
  k_gemm1   <<<dim3(1024),      256, 0, stream>>>(Xbf, WT, h2T);
  k_smt     <<<dim3(16, 64),    256, 0, stream>>>(adj, left, right, coefsT);
  k_gemm2   <<<dim3(1024),      256, 0, stream>>>(coefsT, h2T, out);
}

// Round 7
// 189.776 us; speedup vs baseline: 3.2203x; 1.0324x over previous
//
#include <hip/hip_runtime.h>
#include <cstdint>

typedef __attribute__((ext_vector_type(8))) short short8;
typedef __attribute__((ext_vector_type(4))) float f32x4;

// ---------- helpers ----------
__device__ __forceinline__ unsigned short f2bf(float x) {
  unsigned int u = __float_as_uint(x);
  u += 0x7FFFu + ((u >> 16) & 1u);   // round-to-nearest-even
  return (unsigned short)(u >> 16);
}

#define GLOAD16(gsrc, ldst)                                                        \
  __builtin_amdgcn_global_load_lds(                                                \
      (const __attribute__((address_space(1))) void*)(gsrc),                       \
      (__attribute__((address_space(3))) void*)(ldst), 16, 0, 0)

// ---------- 0b. WT[d][k] = bf16(W2[k][d]) ----------
__global__ __launch_bounds__(256) void k_wt(const float* __restrict__ W,
                                            unsigned short* __restrict__ WT) {
  __shared__ float t[64][68];
  const int k0 = blockIdx.y * 64, d0 = blockIdx.x * 64;
  for (int idx = threadIdx.x; idx < 4096; idx += 256) {
    int r = idx >> 6, c = idx & 63;
    t[r][c] = W[(size_t)(k0 + r) * 512 + d0 + c];
  }
  __syncthreads();
  for (int idx = threadIdx.x; idx < 4096; idx += 256) {
    int r = idx >> 6, c = idx & 63;     // r = d-local, c = k-local
    WT[(size_t)(d0 + r) * 512 + k0 + c] = f2bf(t[c][r]);
  }
}

// ---------- gate 1: rpart[t][kc][col][n] = partial (q @ W1[t]) ----------
__global__ __launch_bounds__(256) void k_gate1(const float* __restrict__ q,
                                               const float* __restrict__ W1,
                                               float* __restrict__ rpart) {
  const int c0 = blockIdx.x * 64;
  const int k0 = blockIdx.y * 128;
  const int t  = blockIdx.z;
  const int tid = threadIdx.x;
  const int lane = tid & 63;           // row n
  const int wcs = __builtin_amdgcn_readfirstlane(tid >> 6);
  __shared__ float qs[64][133];
  for (int idx = tid; idx < 2048; idx += 256) {
    int r = idx >> 5, c4 = (idx & 31) * 4;
    float4 f = *(const float4*)&q[(size_t)r * 512 + k0 + c4];
    qs[r][c4 + 0] = f.x; qs[r][c4 + 1] = f.y;
    qs[r][c4 + 2] = f.z; qs[r][c4 + 3] = f.w;
  }
  __syncthreads();
  const float* Wp = W1 + ((size_t)t * 512 + k0) * 1024 + c0 + wcs * 16;
  float acc[16] = {};
  for (int k = 0; k < 128; ++k) {
    float qr = qs[lane][k];
    const float* wr = Wp + (size_t)k * 1024;
    float4 w0 = *(const float4*)(wr);
    float4 w1 = *(const float4*)(wr + 4);
    float4 w2 = *(const float4*)(wr + 8);
    float4 w3 = *(const float4*)(wr + 12);
    acc[0]  = fmaf(qr, w0.x, acc[0]);  acc[1]  = fmaf(qr, w0.y, acc[1]);
    acc[2]  = fmaf(qr, w0.z, acc[2]);  acc[3]  = fmaf(qr, w0.w, acc[3]);
    acc[4]  = fmaf(qr, w1.x, acc[4]);  acc[5]  = fmaf(qr, w1.y, acc[5]);
    acc[6]  = fmaf(qr, w1.z, acc[6]);  acc[7]  = fmaf(qr, w1.w, acc[7]);
    acc[8]  = fmaf(qr, w2.x, acc[8]);  acc[9]  = fmaf(qr, w2.y, acc[9]);
    acc[10] = fmaf(qr, w2.z, acc[10]); acc[11] = fmaf(qr, w2.w, acc[11]);
    acc[12] = fmaf(qr, w3.x, acc[12]); acc[13] = fmaf(qr, w3.y, acc[13]);
    acc[14] = fmaf(qr, w3.z, acc[14]); acc[15] = fmaf(qr, w3.w, acc[15]);
  }
  float* rp = rpart + ((size_t)(t * 4 + blockIdx.y) * 1024 + c0 + wcs * 16) * 64 + lane;
#pragma unroll
  for (int cc = 0; cc < 16; ++cc) rp[(size_t)cc * 64] = acc[cc];
}

// ---------- gate 2: gpart[t][kc][col][n] = partial (relu(r) @ W2[t]) ----------
__global__ __launch_bounds__(256) void k_gate2(const float* __restrict__ rpart,
                                               const float* __restrict__ W2,
                                               float* __restrict__ gpart) {
  const int c0 = blockIdx.x * 64;
  const int k0 = blockIdx.y * 128;
  const int t  = blockIdx.z;
  const int tid = threadIdx.x;
  const int lane = tid & 63;
  const int wcs = __builtin_amdgcn_readfirstlane(tid >> 6);
  __shared__ float qs[64][133];
  for (int idx = tid; idx < 2048; idx += 256) {
    int kl = idx >> 4, n4 = (idx & 15) * 4;
    const float* rp = rpart + ((size_t)t * 4 * 1024 + k0 + kl) * 64 + n4;
    float4 a = *(const float4*)(rp);
    float4 b = *(const float4*)(rp + 65536);
    float4 c = *(const float4*)(rp + 131072);
    float4 d = *(const float4*)(rp + 196608);
    qs[n4 + 0][kl] = fmaxf(a.x + b.x + c.x + d.x, 0.f);
    qs[n4 + 1][kl] = fmaxf(a.y + b.y + c.y + d.y, 0.f);
    qs[n4 + 2][kl] = fmaxf(a.z + b.z + c.z + d.z, 0.f);
    qs[n4 + 3][kl] = fmaxf(a.w + b.w + c.w + d.w, 0.f);
  }
  __syncthreads();
  const float* Wp = W2 + ((size_t)t << 20) + (size_t)k0 * 1024 + c0 + wcs * 16;
  float acc[16] = {};
  for (int k = 0; k < 128; ++k) {
    float qr = qs[lane][k];
    const float* wr = Wp + (size_t)k * 1024;
    float4 w0 = *(const float4*)(wr);
    float4 w1 = *(const float4*)(wr + 4);
    float4 w2 = *(const float4*)(wr + 8);
    float4 w3 = *(const float4*)(wr + 12);
    acc[0]  = fmaf(qr, w0.x, acc[0]);  acc[1]  = fmaf(qr, w0.y, acc[1]);
    acc[2]  = fmaf(qr, w0.z, acc[2]);  acc[3]  = fmaf(qr, w0.w, acc[3]);
    acc[4]  = fmaf(qr, w1.x, acc[4]);  acc[5]  = fmaf(qr, w1.y, acc[5]);
    acc[6]  = fmaf(qr, w1.z, acc[6]);  acc[7]  = fmaf(qr, w1.w, acc[7]);
    acc[8]  = fmaf(qr, w2.x, acc[8]);  acc[9]  = fmaf(qr, w2.y, acc[9]);
    acc[10] = fmaf(qr, w2.z, acc[10]); acc[11] = fmaf(qr, w2.w, acc[11]);
    acc[12] = fmaf(qr, w3.x, acc[12]); acc[13] = fmaf(qr, w3.y, acc[13]);
    acc[14] = fmaf(qr, w3.z, acc[14]); acc[15] = fmaf(qr, w3.w, acc[15]);
  }
  float* gp = gpart + ((size_t)(t * 8 + blockIdx.y) * 1024 + c0 + wcs * 16) * 64 + lane;
#pragma unroll
  for (int cc = 0; cc < 16; ++cc) gp[(size_t)cc * 64] = acc[cc];
}

// ---------- gate fin: sigmoid(sum) * a -> galT/garT ----------
__global__ __launch_bounds__(256) void k_gate_fin(const float* __restrict__ gpart,
                                                  const float* __restrict__ a_type,
                                                  float* __restrict__ galT,
                                                  float* __restrict__ garT) {
  const int t = blockIdx.y;
  const int n = threadIdx.x & 63;
  const int mg = blockIdx.x * 4 + (threadIdx.x >> 6);
  float s = 0.f;
#pragma unroll
  for (int kc = 0; kc < 8; ++kc)
    s += gpart[((size_t)(t * 8 + kc) * 1024 + mg) * 64 + n];
  float g = 1.f / (1.f + __expf(-s));
  float ga = g * a_type[t * 1024 + mg];
  if (mg < 512) galT[((size_t)t * 512 + mg) * 64 + n] = ga;
  else          garT[((size_t)t * 512 + (mg - 512)) * 64 + n] = ga;
}

// ---------- 3. u,v split-d partials ----------
__global__ __launch_bounds__(256) void k_uvp(const float* __restrict__ W,
                                             const float* __restrict__ galT,
                                             const float* __restrict__ garT,
                                             float* __restrict__ upart,
                                             float* __restrict__ vpart) {
  const int k0 = blockIdx.x * 64;
  const int d0 = blockIdx.y * 64;
  const int t  = blockIdx.z;
  const int tid = threadIdx.x;
  const int lane = tid & 63;           // lane = n
  const int wk = (tid >> 6) * 16;      // wave's k-subtile
  __shared__ float gal_s[64][64];      // [d][n]
  __shared__ float gar_s[64][64];
  __shared__ float W_s[64][64];        // [k][d]
  for (int idx = tid; idx < 1024; idx += 256) {
    int d = idx >> 4, n4 = (idx & 15) * 4;
    *(float4*)&gal_s[d][n4] = *(const float4*)&galT[((size_t)t * 512 + d0 + d) * 64 + n4];
    *(float4*)&gar_s[d][n4] = *(const float4*)&garT[((size_t)t * 512 + d0 + d) * 64 + n4];
    int k = idx >> 4, d4 = (idx & 15) * 4;
    *(float4*)&W_s[k][d4] = *(const float4*)&W[((size_t)t * 512 + k0 + k) * 512 + d0 + d4];
  }
  __syncthreads();
  float au[16] = {}, av[16] = {};
  for (int dq = 0; dq < 64; dq += 4) {
    float g1[4], g2[4];
#pragma unroll
    for (int e = 0; e < 4; ++e) { g1[e] = gal_s[dq + e][lane]; g2[e] = gar_s[dq + e][lane]; }
#pragma unroll
    for (int kk = 0; kk < 16; ++kk) {
      float4 wv = *(const float4*)&W_s[wk + kk][dq];
      au[kk] = fmaf(wv.x, g1[0], fmaf(wv.y, g1[1], fmaf(wv.z, g1[2], fmaf(wv.w, g1[3], au[kk]))));
      av[kk] = fmaf(wv.x, g2[0], fmaf(wv.y, g2[1], fmaf(wv.z, g2[2], fmaf(wv.w, g2[3], av[kk]))));
    }
  }
  const size_t ob = ((size_t)((t * 8 + blockIdx.y) * 64 + lane)) * 512 + k0 + wk;
#pragma unroll
  for (int q = 0; q < 4; ++q) {
    *(float4*)&upart[ob + q * 4] = make_float4(au[q*4], au[q*4+1], au[q*4+2], au[q*4+3]);
    *(float4*)&vpart[ob + q * 4] = make_float4(av[q*4], av[q*4+1], av[q*4+2], av[q*4+3]);
  }
}

// ---------- 3b. sum uv partials -> uvbf[n][6][512] bf16 ----------
__global__ __launch_bounds__(256) void k_uvsum(const float* __restrict__ upart,
                                               const float* __restrict__ vpart,
                                               unsigned short* __restrict__ uvbf) {
  const int n = blockIdx.x;
  for (int idx = threadIdx.x; idx < 768; idx += 256) {
    int col = idx >> 7;              // 0..5
    int k4 = (idx & 127) * 4;
    const float* base = (col < 3)
        ? upart + ((size_t)(col * 8) * 64 + n) * 512 + k4
        : vpart + ((size_t)((col - 3) * 8) * 64 + n) * 512 + k4;
    float4 sv = {0.f, 0.f, 0.f, 0.f};
#pragma unroll
    for (int dc = 0; dc < 8; ++dc) {
      float4 t = *(const float4*)(base + (size_t)dc * 32768);
      sv.x += t.x; sv.y += t.y; sv.z += t.z; sv.w += t.w;
    }
    ushort4 o;
    o.x = f2bf(sv.x); o.y = f2bf(sv.y); o.z = f2bf(sv.z); o.w = f2bf(sv.w);
    *(ushort4*)&uvbf[((size_t)n * 6 + col) * 512 + k4] = o;
  }
}

// ---------- 4. k_lrm: single pass over X: f32->bf16 conversion + left/right via MFMA ----------
__global__ __launch_bounds__(256) void k_lrm(const float* __restrict__ x,
                                             const unsigned short* __restrict__ uvbf,
                                             float* __restrict__ left,
                                             float* __restrict__ right,
                                             unsigned short* __restrict__ Xbf) {
  const int n  = blockIdx.y;
  const int i0 = blockIdx.x * 64;
  const int tid = threadIdx.x;
  const int lane = tid & 63, wid = tid >> 6;
  __shared__ unsigned short uvs[16][520];
  __shared__ __attribute__((aligned(16))) char As[4096];

  for (int idx = tid; idx < 16 * 64; idx += 256) {
    int col = idx >> 6, k8 = (idx & 63) * 8;
    ushort4 z0 = {0, 0, 0, 0}, z1 = {0, 0, 0, 0};
    if (col < 6) {
      const unsigned short* p = uvbf + ((size_t)n * 6 + col) * 512 + k8;
      z0 = *(const ushort4*)p;
      z1 = *(const ushort4*)(p + 4);
    }
    *(ushort4*)&uvs[col][k8]     = z0;
    *(ushort4*)&uvs[col][k8 + 4] = z1;
  }
  const int row = tid >> 2, sub = tid & 3;
  const float* gp = x + ((size_t)n * 512 + i0 + row) * 512 + sub * 8;
  unsigned short* xp = Xbf + ((size_t)n * 512 + i0 + row) * 512 + sub * 8;
  const int lds_off = row * 64 + ((sub ^ (row & 3)) << 4);
  const int arow = wid * 16 + (lane & 15);
  const int a_off = arow * 64 + (((lane >> 4) ^ (arow & 3)) << 4);
  f32x4 acc = {0.f, 0.f, 0.f, 0.f};
  float4 f0 = *(const float4*)(gp);
  float4 f1 = *(const float4*)(gp + 4);
  __syncthreads();
  for (int s = 0; s < 16; ++s) {
    uint4 pk;
    pk.x = ((unsigned)f2bf(f0.y) << 16) | f2bf(f0.x);
    pk.y = ((unsigned)f2bf(f0.w) << 16) | f2bf(f0.z);
    pk.z = ((unsigned)f2bf(f1.y) << 16) | f2bf(f1.x);
    pk.w = ((unsigned)f2bf(f1.w) << 16) | f2bf(f1.z);
    if (s < 15) {
      f0 = *(const float4*)(gp + (s + 1) * 32);
      f1 = *(const float4*)(gp + (s + 1) * 32 + 4);
    }
    *(uint4*)(xp + s * 32) = pk;
    *(uint4*)(As + lds_off) = pk;
    __syncthreads();
    short8 a = *(const short8*)(As + a_off);
    short8 b = *(const short8*)&uvs[lane & 15][s * 32 + (lane >> 4) * 8];
    acc = __builtin_amdgcn_mfma_f32_16x16x32_bf16(a, b, acc, 0, 0, 0);
    __syncthreads();
  }
  const int col = lane & 15;
  if (col < 6) {
    float* dst = (col < 3) ? left : right;
    const int t = (col < 3) ? col : col - 3;
    const int i = i0 + wid * 16 + ((lane >> 4) << 2);
    float* p = dst + ((size_t)t * 64 + n) * 512 + i;
    p[0] = acc.x; p[1] = acc.y; p[2] = acc.z; p[3] = acc.w;
  }
}

// ---------- 5. MFMA GEMM1: h2T[n][d][i] = (X[n] @ W2)^T ; XCD-swizzled, LDS-transposed store ----------
__global__ __launch_bounds__(256) void k_gemm1(const unsigned short* __restrict__ X,
                                               const unsigned short* __restrict__ WT,
                                               unsigned short* __restrict__ h2T) {
  __shared__ __attribute__((aligned(16))) char smem[34816];
  char* As = smem;
  char* Bs = smem + 8192;
  const int s = blockIdx.x;
  const int n  = ((s >> 7) << 3) | (s & 7);
  const int jj = (s >> 3) & 15;
  const int i0 = (jj >> 2) * 128;
  const int d0 = (jj & 3) * 128;
  const int tid = threadIdx.x;
  const int lane = tid & 63, w = tid >> 6;
  const int wm = w >> 1, wn = w & 1;
  const int srow = tid >> 2;
  const int kbp  = tid & 3;
  f32x4 acc[4][4];
#pragma unroll
  for (int a = 0; a < 4; ++a)
#pragma unroll
    for (int b = 0; b < 4; ++b) acc[a][b] = (f32x4){0.f, 0.f, 0.f, 0.f};

  const size_t xbase = (size_t)n * 262144;
  int ra[4], rb[4];
#pragma unroll
  for (int f = 0; f < 4; ++f) {
    int row = wm * 64 + f * 16 + (lane & 15);
    ra[f] = row * 64 + (((lane >> 4) ^ ((row >> 1) & 3)) << 4);
    int rowb = wn * 64 + f * 16 + (lane & 15);
    rb[f] = rowb * 64 + (((lane >> 4) ^ ((rowb >> 1) & 3)) << 4);
  }
  const int kl0 = (kbp ^ ((srow >> 1) & 3)) * 8;
  const int kl1 = (kbp ^ (((64 + srow) >> 1) & 3)) * 8;

  for (int kc = 0; kc < 512; kc += 32) {
    __syncthreads();
    GLOAD16(X + xbase + (size_t)(i0 + srow) * 512 + kc + kl0,       As + tid * 16);
    GLOAD16(X + xbase + (size_t)(i0 + 64 + srow) * 512 + kc + kl1,  As + 4096 + tid * 16);
    GLOAD16(WT + (size_t)(d0 + srow) * 512 + kc + kl0,              Bs + tid * 16);
    GLOAD16(WT + (size_t)(d0 + 64 + srow) * 512 + kc + kl1,         Bs + 4096 + tid * 16);
    __syncthreads();
    short8 a[4], b[4];
#pragma unroll
    for (int f = 0; f < 4; ++f) a[f] = *(const short8*)(As + ra[f]);
#pragma unroll
    for (int f = 0; f < 4; ++f) b[f] = *(const short8*)(Bs + rb[f]);
#pragma unroll
    for (int mf = 0; mf < 4; ++mf)
#pragma unroll
      for (int nf = 0; nf < 4; ++nf)
        acc[mf][nf] = __builtin_amdgcn_mfma_f32_16x16x32_bf16(a[mf], b[nf], acc[mf][nf], 0, 0, 0);
  }
  __syncthreads();
  unsigned short (*Ct)[136] = (unsigned short (*)[136])smem;
#pragma unroll
  for (int mf = 0; mf < 4; ++mf)
#pragma unroll
    for (int nf = 0; nf < 4; ++nf) {
      f32x4 vv = acc[mf][nf];
      int dl = wn * 64 + nf * 16 + (lane & 15);
      int il = wm * 64 + mf * 16 + ((lane >> 4) << 2);
      ushort4 pk;
      pk.x = f2bf(vv.x); pk.y = f2bf(vv.y); pk.z = f2bf(vv.z); pk.w = f2bf(vv.w);
      *(ushort4*)&Ct[dl][il] = pk;
    }
  __syncthreads();
  const size_t obase = xbase + (size_t)d0 * 512 + i0;
#pragma unroll
  for (int q = 0; q < 8; ++q) {
    int f = q * 2048 + tid * 8;
    int dl = f >> 7, il = f & 127;
    *(uint4*)&h2T[obase + (size_t)dl * 512 + il] = *(const uint4*)&Ct[dl][il];
  }
}

// ---------- 6. fused masked softmax + transpose -> coefsT[n][j][i] bf16 ----------
// grid (32 i-tiles of 16, 64 n), 256 thr / 4 waves; each wave owns 4 rows,
// processed stage-interleaved (loads -> scores -> 4 interleaved max-reduces ->
// 4 interleaved exp+sum-reduces -> LDS transpose). LDS = 24.8 KB -> 6 blocks/CU.
__global__ __launch_bounds__(256) void k_smt(const int* __restrict__ adj,
                                             const float* __restrict__ left,
                                             const float* __restrict__ right,
                                             unsigned short* __restrict__ ct) {
  const int n  = blockIdx.y;
  const int i0 = blockIdx.x * 16;
  const int tid = threadIdx.x;
  const int lane = tid & 63, wid = tid >> 6;
  __shared__ float rs[3][512];               //  6144 B
  __shared__ float ls[3][16];                //   192 B
  __shared__ unsigned short tile[512][18];   // 18432 B, pitch 9 dwords -> conflict-free
  for (int idx = tid; idx < 1536; idx += 256) {
    int t = idx >> 9, j = idx & 511;
    rs[t][j] = right[((size_t)t * 64 + n) * 512 + j];
  }
  if (tid < 48) {
    int t = tid >> 4, il = tid & 15;
    ls[t][il] = left[((size_t)t * 64 + n) * 512 + i0 + il];
  }
  __syncthreads();
  const int* adjb = adj + ((size_t)n * 512 + i0) * 512;
  // all 32 adj loads issued upfront (4 rows x 8 j-groups)
  int tv[4][8];
#pragma unroll
  for (int r = 0; r < 4; ++r)
#pragma unroll
    for (int e = 0; e < 8; ++e)
      tv[r][e] = adjb[(size_t)(wid * 4 + r) * 512 + e * 64 + lane];
  float s[4][8];
#pragma unroll
  for (int r = 0; r < 4; ++r) {
    const int il = wid * 4 + r;
    const float l0 = ls[0][il], l1 = ls[1][il], l2 = ls[2][il];
#pragma unroll
    for (int e = 0; e < 8; ++e) {
      int t = tv[r][e];
      if (t == 0) s[r][e] = -9e15f;
      else {
        float lv = (t == 1) ? l0 : (t == 2) ? l1 : l2;
        float xv = lv + rs[t - 1][e * 64 + lane];
        s[r][e] = (xv >= 0.f) ? xv : 0.2f * xv;
      }
    }
  }
  float m[4];
#pragma unroll
  for (int r = 0; r < 4; ++r)
    m[r] = fmaxf(fmaxf(fmaxf(s[r][0], s[r][1]), fmaxf(s[r][2], s[r][3])),
                 fmaxf(fmaxf(s[r][4], s[r][5]), fmaxf(s[r][6], s[r][7])));
  for (int off = 32; off > 0; off >>= 1) {
#pragma unroll
    for (int r = 0; r < 4; ++r) m[r] = fmaxf(m[r], __shfl_xor(m[r], off));
  }
  float sum[4] = {0.f, 0.f, 0.f, 0.f};
#pragma unroll
  for (int r = 0; r < 4; ++r)
#pragma unroll
    for (int e = 0; e < 8; ++e) {
      s[r][e] = __expf(s[r][e] - m[r]);
      sum[r] += s[r][e];
    }
  for (int off = 32; off > 0; off >>= 1) {
#pragma unroll
    for (int r = 0; r < 4; ++r) sum[r] += __shfl_xor(sum[r], off);
  }
#pragma unroll
  for (int r = 0; r < 4; ++r) {
    const float inv = 1.f / sum[r];
    const int il = wid * 4 + r;
#pragma unroll
    for (int e = 0; e < 8; ++e)
      tile[e * 64 + lane][il] = f2bf(s[r][e] * inv);
  }
  __syncthreads();
  // writeout: 4 passes; thread -> (j = pass*128 + tid>>1, i8 = (tid&1)*8)
  unsigned short* ob = ct + (size_t)n * 262144 + i0;
#pragma unroll
  for (int pass = 0; pass < 4; ++pass) {
    int j = pass * 128 + (tid >> 1);
    int i8 = (tid & 1) * 8;
    const unsigned short* tp = &tile[j][i8];
    uint4 o;
    o.x = *(const unsigned int*)(tp);
    o.y = *(const unsigned int*)(tp + 2);
    o.z = *(const unsigned int*)(tp + 4);
    o.w = *(const unsigned int*)(tp + 6);
    *(uint4*)&ob[(size_t)j * 512 + i8] = o;
  }
}

// ---------- 8. MFMA GEMM2: out[n][j][d] = coefsT[n] @ h2T[n]^T ; XCD-swizzled ----------
__global__ __launch_bounds__(256) void k_gemm2(const unsigned short* __restrict__ CT,
                                               const unsigned short* __restrict__ H2T,
                                               float* __restrict__ out) {
  const int s = blockIdx.x;
  const int n  = ((s >> 7) << 3) | (s & 7);
  const int jj = (s >> 3) & 15;
  const int j0 = (jj >> 2) * 128;
  const int d0 = (jj & 3) * 128;
  const int tid = threadIdx.x;
  const int lane = tid & 63, w = tid >> 6;
  const int wm = w >> 1, wn = w & 1;
  __shared__ __attribute__((aligned(16))) char As[8192];
  __shared__ __attribute__((aligned(16))) char Bs[8192];
  const int srow = tid >> 2;
  const int kbp  = tid & 3;
  f32x4 acc[4][4];
#pragma unroll
  for (int a = 0; a < 4; ++a)
#pragma unroll
    for (int b = 0; b < 4; ++b) acc[a][b] = (f32x4){0.f, 0.f, 0.f, 0.f};

  const size_t base = (size_t)n * 262144;
  int ra[4], rb[4];
#pragma unroll
  for (int f = 0; f < 4; ++f) {
    int row = wm * 64 + f * 16 + (lane & 15);
    ra[f] = row * 64 + (((lane >> 4) ^ ((row >> 1) & 3)) << 4);
    int rowb = wn * 64 + f * 16 + (lane & 15);
    rb[f] = rowb * 64 + (((lane >> 4) ^ ((rowb >> 1) & 3)) << 4);
  }
  const int kl0 = (kbp ^ ((srow >> 1) & 3)) * 8;
  const int kl1 = (kbp ^ (((64 + srow) >> 1) & 3)) * 8;

  for (int kc = 0; kc < 512; kc += 32) {
    __syncthreads();
    GLOAD16(CT + base + (size_t)(j0 + srow) * 512 + kc + kl0,       As + tid * 16);
    GLOAD16(CT + base + (size_t)(j0 + 64 + srow) * 512 + kc + kl1,  As + 4096 + tid * 16);
    GLOAD16(H2T + base + (size_t)(d0 + srow) * 512 + kc + kl0,      Bs + tid * 16);
    GLOAD16(H2T + base + (size_t)(d0 + 64 + srow) * 512 + kc + kl1, Bs + 4096 + tid * 16);
    __syncthreads();
    short8 a[4], b[4];
#pragma unroll
    for (int f = 0; f < 4; ++f) a[f] = *(const short8*)(As + ra[f]);
#pragma unroll
    for (int f = 0; f < 4; ++f) b[f] = *(const short8*)(Bs + rb[f]);
#pragma unroll
    for (int mf = 0; mf < 4; ++mf)
#pragma unroll
      for (int nf = 0; nf < 4; ++nf)
        acc[mf][nf] = __builtin_amdgcn_mfma_f32_16x16x32_bf16(a[mf], b[nf], acc[mf][nf], 0, 0, 0);
  }
  const int jb = j0 + wm * 64 + (lane >> 4) * 4;
  const int db = d0 + wn * 64 + (lane & 15);
#pragma unroll
  for (int mf = 0; mf < 4; ++mf)
#pragma unroll
    for (int nf = 0; nf < 4; ++nf) {
      f32x4 vv = acc[mf][nf];
      float* op = out + base + (size_t)(jb + mf * 16) * 512 + db + nf * 16;
      op[0]    = vv.x;
      op[512]  = vv.y;
      op[1024] = vv.z;
      op[1536] = vv.w;
    }
}

extern "C" void kernel_launch(void* const* d_in, const int* in_sizes, int n_in,
                              void* d_out, int out_size, void* d_ws, size_t ws_size,
                              hipStream_t stream) {
  const float* input  = (const float*)d_in[0];
  const int*   adj    = (const int*)d_in[1];
  const float* query  = (const float*)d_in[3];
  const float* W_type = (const float*)d_in[4];
  const float* a_type = (const float*)d_in[5];
  const float* W1     = (const float*)d_in[6];
  const float* W2     = (const float*)d_in[7];
  float* out = (float*)d_out;

  char* ws = (char*)d_ws;
  float* galT  = (float*)(ws);                              //  393,216 B
  float* garT  = (float*)(ws + 393216);                     //  393,216 B
  unsigned short* uvbf = (unsigned short*)(ws + 786432);    //  393,216 B
  float* left  = (float*)(ws + 1179648);                    //  393,216 B
  float* right = (float*)(ws + 1572864);                    //  393,216 B
  unsigned short* Xbf = (unsigned short*)(ws + 2359296);    // 33,554,432 B (reused as coefsT)
  unsigned short* h2T = (unsigned short*)(ws + 35913728);   // 33,554,432 B
  // partials alias h2T's region: all dead before k_gemm1 writes h2T
  float* rpart = (float*)(ws + 35913728);                   //  3,145,728 B
  float* gpart = (float*)(ws + 39059456);                   //  6,291,456 B
  float* upart = (float*)(ws + 45350912);                   //  3,145,728 B
  float* vpart = (float*)(ws + 48496640);                   //  3,145,728 B
  unsigned short* WT  = (unsigned short*)(ws + 69468160);   //    524,288 B
  // total ws use: 69,992,448 B
  unsigned short* coefsT = Xbf;   // Xbf dead after k_gemm1; k_smt writes it, k_gemm2 reads it

  k_wt      <<<dim3(8, 8),      256, 0, stream>>>(W_type + (size_t)2 * 262144, WT);
  k_gate1   <<<dim3(16, 4, 3),  256, 0, stream>>>(query, W1, rpart);
  k_gate2   <<<dim3(16, 8, 3),  256, 0, stream>>>(rpart, W2, gpart);
  k_gate_fin<<<dim3(256, 3),    256, 0, stream>>>(gpart, a_type, galT, garT);
  k_uvp     <<<dim3(8, 8, 3),   256, 0, stream>>>(W_type, galT, garT, upart, vpart);
  k_uvsum   <<<dim3(64),        256, 0, stream>>>(upart, vpart, uvbf);
  k_lrm     <<<dim3(8, 64),     256, 0, stream>>>(input, uvbf, left, right, Xbf);
  k_gemm1   <<<dim3(1024),      256, 0, stream>>>(Xbf, WT, h2T);
  k_smt     <<<dim3(32, 64),    256, 0, stream>>>(adj, left, right, coefsT);
  k_gemm2   <<<dim3(1024),      256, 0, stream>>>(coefsT, h2T, out);
}